// Round 1
// baseline (1304.797 us; speedup 1.0000x reference)
//
#include <hip/hip_runtime.h>
#include <math.h>

#define NN 100000
#define NE 1600000
#define NG 128
#define H 128

// ---------------- CSR build ----------------
__global__ void k_hist(const int* __restrict__ ei, int* __restrict__ cnt) {
  int e = blockIdx.x * blockDim.x + threadIdx.x;
  if (e < NE) atomicAdd(&cnt[ei[NE + e]], 1);
}

#define SCAN_B 1024
#define SCAN_GRID 98  // ceil(100000/1024)

__global__ void k_scan1(const int* __restrict__ cnt, int* __restrict__ rowptr1,
                        int* __restrict__ bsums) {
  __shared__ int s[SCAN_B];
  int tid = threadIdx.x;
  int gid = blockIdx.x * SCAN_B + tid;
  int v = (gid < NN) ? cnt[gid] : 0;
  s[tid] = v;
  __syncthreads();
  for (int off = 1; off < SCAN_B; off <<= 1) {
    int t = (tid >= off) ? s[tid - off] : 0;
    __syncthreads();
    s[tid] += t;
    __syncthreads();
  }
  if (gid < NN) rowptr1[gid] = s[tid];
  if (tid == SCAN_B - 1) bsums[blockIdx.x] = s[tid];
}

__global__ void k_scan2(int* __restrict__ bsums) {
  __shared__ int s[128];
  int tid = threadIdx.x;
  int v = (tid < SCAN_GRID) ? bsums[tid] : 0;
  s[tid] = v;
  __syncthreads();
  for (int off = 1; off < 128; off <<= 1) {
    int t = (tid >= off) ? s[tid - off] : 0;
    __syncthreads();
    s[tid] += t;
    __syncthreads();
  }
  if (tid < SCAN_GRID) bsums[tid] = s[tid];
}

__global__ void k_scan3(int* __restrict__ rowptr, const int* __restrict__ bsums,
                        int* __restrict__ cnt_to_fill) {
  int gid = blockIdx.x * SCAN_B + threadIdx.x;
  if (gid >= NN) return;
  int add = (blockIdx.x > 0) ? bsums[blockIdx.x - 1] : 0;
  int incl = rowptr[gid + 1] + add;
  rowptr[gid + 1] = incl;
  cnt_to_fill[gid] = incl - cnt_to_fill[gid];  // exclusive prefix -> fillptr
  if (gid == 0) rowptr[0] = 0;
}

__global__ void k_fill(const int* __restrict__ ei, int* __restrict__ fillptr,
                       int* __restrict__ col) {
  int e = blockIdx.x * blockDim.x + threadIdx.x;
  if (e >= NE) return;
  int s = ei[e];
  int d = ei[NE + e];
  int pos = atomicAdd(&fillptr[d], 1);
  col[pos] = s;
}

// ---------------- aggregation ----------------
// one wave (64 lanes) per node; lane holds 2 fp32 columns (float2)
__global__ void k_agg128(const float* __restrict__ x, const int* __restrict__ rowptr,
                         const int* __restrict__ col, float* __restrict__ agg) {
  int w = (blockIdx.x * blockDim.x + threadIdx.x) >> 6;
  int lane = threadIdx.x & 63;
  if (w >= NN) return;
  int beg = rowptr[w], end = rowptr[w + 1];
  float2 acc = make_float2(0.f, 0.f);
  int e = beg;
  for (; e + 1 < end; e += 2) {  // 2 independent chains to hide gather latency
    int s0 = col[e], s1 = col[e + 1];
    float2 v0 = ((const float2*)(x + (size_t)s0 * H))[lane];
    float2 v1 = ((const float2*)(x + (size_t)s1 * H))[lane];
    acc.x += v0.x + v1.x;
    acc.y += v0.y + v1.y;
  }
  if (e < end) {
    float2 v = ((const float2*)(x + (size_t)col[e] * H))[lane];
    acc.x += v.x;
    acc.y += v.y;
  }
  ((float2*)(agg + (size_t)w * H))[lane] = acc;
}

// layer-1 aggregation in F_IN=4 space (aggregate BEFORE matmul: 25 MB not 819 MB)
__global__ void k_agg4(const float* __restrict__ x, const int* __restrict__ rowptr,
                       const int* __restrict__ col, float* __restrict__ agg4) {
  int i = blockIdx.x * blockDim.x + threadIdx.x;
  if (i >= NN) return;
  int beg = rowptr[i], end = rowptr[i + 1];
  float4 acc = make_float4(0.f, 0.f, 0.f, 0.f);
  for (int e = beg; e < end; ++e) {
    float4 v = ((const float4*)x)[col[e]];
    acc.x += v.x; acc.y += v.y; acc.z += v.z; acc.w += v.w;
  }
  ((float4*)agg4)[i] = acc;
}

// ---------------- layer-1 GEMM (K=4+4) ----------------
__global__ void k_gemm4(const float* __restrict__ agg4, const float* __restrict__ x4,
                        const float* __restrict__ Wr, const float* __restrict__ Wo,
                        const float* __restrict__ br, float* __restrict__ out) {
  __shared__ float sWr[512], sWo[512], sbr[128];
  int tid = threadIdx.x;
  sWr[tid] = Wr[tid]; sWr[tid + 256] = Wr[tid + 256];
  sWo[tid] = Wo[tid]; sWo[tid + 256] = Wo[tid + 256];
  if (tid < 128) sbr[tid] = br[tid];
  __syncthreads();
  int node = blockIdx.x * 2 + (tid >> 7);
  int j = tid & 127;
  if (node >= NN) return;
  float4 a = ((const float4*)agg4)[node];
  float4 xv = ((const float4*)x4)[node];
  float acc = sbr[j];
  acc = fmaf(a.x, sWr[0 * 128 + j], acc);
  acc = fmaf(a.y, sWr[1 * 128 + j], acc);
  acc = fmaf(a.z, sWr[2 * 128 + j], acc);
  acc = fmaf(a.w, sWr[3 * 128 + j], acc);
  acc = fmaf(xv.x, sWo[0 * 128 + j], acc);
  acc = fmaf(xv.y, sWo[1 * 128 + j], acc);
  acc = fmaf(xv.z, sWo[2 * 128 + j], acc);
  acc = fmaf(xv.w, sWo[3 * 128 + j], acc);
  out[(size_t)node * H + j] = fmaxf(acc, 0.f);
}

// ---------------- main GEMM: relu(agg@Wr + x@Wo + br) ----------------
// block = 256 threads = 256 node-rows; grid.y in {0,1} picks 64-col half so the
// W address is wave-uniform -> compiler scalarizes W to s_load + v_fmac(sgpr).
// A tile staged to LDS k-major with pad-260 stride: compute reads conflict-free.
__global__ __launch_bounds__(256, 2) void k_gemm128(
    const float* __restrict__ A, const float* __restrict__ X,
    const float* __restrict__ Wr, const float* __restrict__ Wo,
    const float* __restrict__ br, float* __restrict__ out, int M) {
  __shared__ float sA[32 * 260];
  const int tid = threadIdx.x;
  const int m0 = blockIdx.x * 256;
  const int jb = blockIdx.y * 64;

  float acc[64];
#pragma unroll
  for (int j = 0; j < 64; ++j) acc[j] = 0.f;

  for (int half = 0; half < 2; ++half) {
    const float* Ap = half ? X : A;
    const float* Wp = half ? Wo : Wr;
    for (int kc = 0; kc < 128; kc += 32) {
      __syncthreads();
#pragma unroll
      for (int i = 0; i < 8; ++i) {
        int lin = i * 256 + tid;  // 2048 float4 loads, coalesced in 128B runs
        int r = lin >> 3;
        int c4 = lin & 7;
        int m = m0 + r;
        float4 v = make_float4(0.f, 0.f, 0.f, 0.f);
        if (m < M) v = *(const float4*)(Ap + (size_t)m * H + kc + c4 * 4);
        int c = c4 * 4;
        sA[(c + 0) * 260 + r] = v.x;
        sA[(c + 1) * 260 + r] = v.y;
        sA[(c + 2) * 260 + r] = v.z;
        sA[(c + 3) * 260 + r] = v.w;
      }
      __syncthreads();
#pragma unroll 4
      for (int k = 0; k < 32; ++k) {
        float a = sA[k * 260 + tid];
        const float* w = Wp + (size_t)(kc + k) * H + jb;  // wave-uniform
#pragma unroll
        for (int j = 0; j < 64; ++j) acc[j] = fmaf(a, w[j], acc[j]);
      }
    }
  }
  int m = m0 + tid;
  if (m < M) {
    float* op = out + (size_t)m * H + jb;
#pragma unroll
    for (int j4 = 0; j4 < 16; ++j4) {
      float4 v;
      v.x = fmaxf(acc[j4 * 4 + 0] + br[jb + j4 * 4 + 0], 0.f);
      v.y = fmaxf(acc[j4 * 4 + 1] + br[jb + j4 * 4 + 1], 0.f);
      v.z = fmaxf(acc[j4 * 4 + 2] + br[jb + j4 * 4 + 2], 0.f);
      v.w = fmaxf(acc[j4 * 4 + 3] + br[jb + j4 * 4 + 3], 0.f);
      *(float4*)(op + j4 * 4) = v;
    }
  }
}

// ---------------- pooling + head ----------------
__global__ void k_bounds(const int* __restrict__ batch, int* __restrict__ gstart) {
  int g = threadIdx.x;
  if (g > NG) return;
  int lo = 0, hi = NN;
  while (lo < hi) {
    int mid = (lo + hi) >> 1;
    if (batch[mid] < g) lo = mid + 1; else hi = mid;
  }
  gstart[g] = lo;
}

__global__ void k_pool(const float* __restrict__ x, const int* __restrict__ gstart,
                       float* __restrict__ g) {
  int gr = blockIdx.x, j = threadIdx.x;
  int beg = gstart[gr], end = gstart[gr + 1];
  float acc = 0.f;
  for (int i = beg; i < end; ++i) acc += x[(size_t)i * H + j];
  float cnt = (float)(end - beg);
  g[gr * H + j] = acc / fmaxf(cnt, 1.f);
}

__global__ void k_head(const float* __restrict__ gin,
                       const float* __restrict__ W5, const float* __restrict__ b5,
                       const float* __restrict__ W6, const float* __restrict__ b6,
                       const float* __restrict__ W7, const float* __restrict__ b7,
                       const float* __restrict__ W8, const float* __restrict__ b8,
                       const float* __restrict__ Wl, const float* __restrict__ bl,
                       float* __restrict__ out) {
  __shared__ float s0[128], s1[128];
  const int g = blockIdx.x, j = threadIdx.x;
  s0[j] = gin[g * 128 + j];
  __syncthreads();
  const float* Ws[4] = {W5, W6, W7, W8};
  const float* bs[4] = {b5, b6, b7, b8};
  float* cur = s0;
  float* nxt = s1;
  for (int L = 0; L < 4; ++L) {
    const float* W = Ws[L];
    float a = bs[L][j];
    for (int k = 0; k < 128; ++k) a = fmaf(cur[k], W[k * 128 + j], a);
    nxt[j] = fmaxf(a, 0.f);
    __syncthreads();
    float* t = cur; cur = nxt; nxt = t;
  }
  if (j < 2) {
    float a = bl[j];
    for (int k = 0; k < 128; ++k) a = fmaf(cur[k], Wl[k * 2 + j], a);
    out[g * 2 + j] = 1.f / (1.f + __expf(-a));
  }
}

// ---------------- launch ----------------
static inline char* ws_take(char*& p, size_t bytes) {
  char* r = p;
  p += (bytes + 255) & ~(size_t)255;
  return r;
}

extern "C" void kernel_launch(void* const* d_in, const int* in_sizes, int n_in,
                              void* d_out, int out_size, void* d_ws, size_t ws_size,
                              hipStream_t stream) {
  const float* x0 = (const float*)d_in[0];
  const int* ei = (const int*)d_in[1];
  const int* batch = (const int*)d_in[2];
  const float* Wr[4] = {(const float*)d_in[3], (const float*)d_in[6],
                        (const float*)d_in[9], (const float*)d_in[12]};
  const float* brr[4] = {(const float*)d_in[4], (const float*)d_in[7],
                         (const float*)d_in[10], (const float*)d_in[13]};
  const float* Wo[4] = {(const float*)d_in[5], (const float*)d_in[8],
                        (const float*)d_in[11], (const float*)d_in[14]};
  const float* W5 = (const float*)d_in[15];
  const float* b5 = (const float*)d_in[16];
  const float* W6 = (const float*)d_in[17];
  const float* b6 = (const float*)d_in[18];
  const float* W7 = (const float*)d_in[19];
  const float* b7 = (const float*)d_in[20];
  const float* W8 = (const float*)d_in[21];
  const float* b8 = (const float*)d_in[22];
  const float* Wl = (const float*)d_in[23];
  const float* bl = (const float*)d_in[24];
  float* out = (float*)d_out;

  char* p = (char*)d_ws;
  int* fillptr = (int*)ws_take(p, (size_t)NN * 4);
  int* rowptr = (int*)ws_take(p, (size_t)(NN + 1) * 4);
  int* bsums = (int*)ws_take(p, 1024 * 4);
  int* gstart = (int*)ws_take(p, (NG + 1) * 4);
  int* col = (int*)ws_take(p, (size_t)NE * 4);
  float* agg = (float*)ws_take(p, (size_t)NN * H * 4);
  float* bufA = (float*)ws_take(p, (size_t)NN * H * 4);
  float* bufB = (float*)ws_take(p, (size_t)NN * H * 4);
  float* gpool = (float*)ws_take(p, (size_t)NG * H * 4);
  (void)ws_size; (void)in_sizes; (void)n_in; (void)out_size;

  hipMemsetAsync(fillptr, 0, (size_t)NN * 4, stream);
  k_hist<<<(NE + 255) / 256, 256, 0, stream>>>(ei, fillptr);
  k_scan1<<<SCAN_GRID, SCAN_B, 0, stream>>>(fillptr, rowptr + 1, bsums);
  k_scan2<<<1, 128, 0, stream>>>(bsums);
  k_scan3<<<SCAN_GRID, SCAN_B, 0, stream>>>(rowptr, bsums, fillptr);
  k_fill<<<(NE + 255) / 256, 256, 0, stream>>>(ei, fillptr, col);

  // layer 1 (F_IN=4): aggregate in input space, then small GEMM
  k_agg4<<<(NN + 255) / 256, 256, 0, stream>>>(x0, rowptr, col, agg);
  k_gemm4<<<NN / 2, 256, 0, stream>>>(agg, x0, Wr[0], Wo[0], brr[0], bufA);

  // layers 2-4
  k_agg128<<<25000, 256, 0, stream>>>(bufA, rowptr, col, agg);
  k_gemm128<<<dim3(391, 2), 256, 0, stream>>>(agg, bufA, Wr[1], Wo[1], brr[1], bufB, NN);
  k_agg128<<<25000, 256, 0, stream>>>(bufB, rowptr, col, agg);
  k_gemm128<<<dim3(391, 2), 256, 0, stream>>>(agg, bufB, Wr[2], Wo[2], brr[2], bufA, NN);
  k_agg128<<<25000, 256, 0, stream>>>(bufA, rowptr, col, agg);
  k_gemm128<<<dim3(391, 2), 256, 0, stream>>>(agg, bufA, Wr[3], Wo[3], brr[3], bufB, NN);

  // mean pool + MLP head + sigmoid
  k_bounds<<<1, 256, 0, stream>>>(batch, gstart);
  k_pool<<<NG, 128, 0, stream>>>(bufB, gstart, gpool);
  k_head<<<NG, 128, 0, stream>>>(gpool, W5, b5, W6, b6, W7, b7, W8, b8, Wl, bl, out);
}

// Round 2
// 1160.699 us; speedup vs baseline: 1.1241x; 1.1241x over previous
//
#include <hip/hip_runtime.h>
#include <math.h>

#define NN 100000
#define NE 1600000
#define NG 128
#define H 128

// ---------------- CSR build ----------------
__global__ void k_hist(const int* __restrict__ ei, int* __restrict__ cnt) {
  int e = blockIdx.x * blockDim.x + threadIdx.x;
  if (e < NE) atomicAdd(&cnt[ei[NE + e]], 1);
}

#define SCAN_B 1024
#define SCAN_GRID 98  // ceil(100000/1024)

__global__ void k_scan1(const int* __restrict__ cnt, int* __restrict__ rowptr1,
                        int* __restrict__ bsums) {
  __shared__ int s[SCAN_B];
  int tid = threadIdx.x;
  int gid = blockIdx.x * SCAN_B + tid;
  int v = (gid < NN) ? cnt[gid] : 0;
  s[tid] = v;
  __syncthreads();
  for (int off = 1; off < SCAN_B; off <<= 1) {
    int t = (tid >= off) ? s[tid - off] : 0;
    __syncthreads();
    s[tid] += t;
    __syncthreads();
  }
  if (gid < NN) rowptr1[gid] = s[tid];
  if (tid == SCAN_B - 1) bsums[blockIdx.x] = s[tid];
}

__global__ void k_scan2(int* __restrict__ bsums) {
  __shared__ int s[128];
  int tid = threadIdx.x;
  int v = (tid < SCAN_GRID) ? bsums[tid] : 0;
  s[tid] = v;
  __syncthreads();
  for (int off = 1; off < 128; off <<= 1) {
    int t = (tid >= off) ? s[tid - off] : 0;
    __syncthreads();
    s[tid] += t;
    __syncthreads();
  }
  if (tid < SCAN_GRID) bsums[tid] = s[tid];
}

__global__ void k_scan3(int* __restrict__ rowptr, const int* __restrict__ bsums,
                        int* __restrict__ cnt_to_fill) {
  int gid = blockIdx.x * SCAN_B + threadIdx.x;
  if (gid >= NN) return;
  int add = (blockIdx.x > 0) ? bsums[blockIdx.x - 1] : 0;
  int incl = rowptr[gid + 1] + add;
  rowptr[gid + 1] = incl;
  cnt_to_fill[gid] = incl - cnt_to_fill[gid];  // exclusive prefix -> fillptr
  if (gid == 0) rowptr[0] = 0;
}

__global__ void k_fill(const int* __restrict__ ei, int* __restrict__ fillptr,
                       int* __restrict__ col) {
  int e = blockIdx.x * blockDim.x + threadIdx.x;
  if (e >= NE) return;
  int s = ei[e];
  int d = ei[NE + e];
  int pos = atomicAdd(&fillptr[d], 1);
  col[pos] = s;
}

// ---------------- aggregation ----------------
// one wave (64 lanes) per node; lane holds 2 fp32 columns (float2)
__global__ void k_agg128(const float* __restrict__ x, const int* __restrict__ rowptr,
                         const int* __restrict__ col, float* __restrict__ agg) {
  int w = (blockIdx.x * blockDim.x + threadIdx.x) >> 6;
  int lane = threadIdx.x & 63;
  if (w >= NN) return;
  int beg = rowptr[w], end = rowptr[w + 1];
  float2 acc = make_float2(0.f, 0.f);
  int e = beg;
  for (; e + 1 < end; e += 2) {  // 2 independent chains to hide gather latency
    int s0 = col[e], s1 = col[e + 1];
    float2 v0 = ((const float2*)(x + (size_t)s0 * H))[lane];
    float2 v1 = ((const float2*)(x + (size_t)s1 * H))[lane];
    acc.x += v0.x + v1.x;
    acc.y += v0.y + v1.y;
  }
  if (e < end) {
    float2 v = ((const float2*)(x + (size_t)col[e] * H))[lane];
    acc.x += v.x;
    acc.y += v.y;
  }
  ((float2*)(agg + (size_t)w * H))[lane] = acc;
}

// layer-1 aggregation in F_IN=4 space (aggregate BEFORE matmul: 25 MB not 819 MB)
__global__ void k_agg4(const float* __restrict__ x, const int* __restrict__ rowptr,
                       const int* __restrict__ col, float* __restrict__ agg4) {
  int i = blockIdx.x * blockDim.x + threadIdx.x;
  if (i >= NN) return;
  int beg = rowptr[i], end = rowptr[i + 1];
  float4 acc = make_float4(0.f, 0.f, 0.f, 0.f);
  for (int e = beg; e < end; ++e) {
    float4 v = ((const float4*)x)[col[e]];
    acc.x += v.x; acc.y += v.y; acc.z += v.z; acc.w += v.w;
  }
  ((float4*)agg4)[i] = acc;
}

// ---------------- layer-1 GEMM (K=4+4) ----------------
__global__ void k_gemm4(const float* __restrict__ agg4, const float* __restrict__ x4,
                        const float* __restrict__ Wr, const float* __restrict__ Wo,
                        const float* __restrict__ br, float* __restrict__ out) {
  __shared__ float sWr[512], sWo[512], sbr[128];
  int tid = threadIdx.x;
  sWr[tid] = Wr[tid]; sWr[tid + 256] = Wr[tid + 256];
  sWo[tid] = Wo[tid]; sWo[tid + 256] = Wo[tid + 256];
  if (tid < 128) sbr[tid] = br[tid];
  __syncthreads();
  int node = blockIdx.x * 2 + (tid >> 7);
  int j = tid & 127;
  if (node >= NN) return;
  float4 a = ((const float4*)agg4)[node];
  float4 xv = ((const float4*)x4)[node];
  float acc = sbr[j];
  acc = fmaf(a.x, sWr[0 * 128 + j], acc);
  acc = fmaf(a.y, sWr[1 * 128 + j], acc);
  acc = fmaf(a.z, sWr[2 * 128 + j], acc);
  acc = fmaf(a.w, sWr[3 * 128 + j], acc);
  acc = fmaf(xv.x, sWo[0 * 128 + j], acc);
  acc = fmaf(xv.y, sWo[1 * 128 + j], acc);
  acc = fmaf(xv.z, sWo[2 * 128 + j], acc);
  acc = fmaf(xv.w, sWo[3 * 128 + j], acc);
  out[(size_t)node * H + j] = fmaxf(acc, 0.f);
}

// ---------------- main GEMM: relu(agg@Wr + x@Wo + br) ----------------
// block = 256 threads = 256 node-rows; grid.y in {0,1} picks 64-col half so the
// W address is wave-uniform -> compiler scalarizes W to s_load + v_fmac(sgpr).
// A tile staged to LDS k-major with pad-260 stride: compute reads conflict-free.
__global__ __launch_bounds__(256, 2) void k_gemm128(
    const float* __restrict__ A, const float* __restrict__ X,
    const float* __restrict__ Wr, const float* __restrict__ Wo,
    const float* __restrict__ br, float* __restrict__ out, int M) {
  __shared__ float sA[32 * 260];
  const int tid = threadIdx.x;
  const int m0 = blockIdx.x * 256;
  const int jb = blockIdx.y * 64;

  float acc[64];
#pragma unroll
  for (int j = 0; j < 64; ++j) acc[j] = 0.f;

  for (int half = 0; half < 2; ++half) {
    const float* Ap = half ? X : A;
    const float* Wp = half ? Wo : Wr;
    for (int kc = 0; kc < 128; kc += 32) {
      __syncthreads();
#pragma unroll
      for (int i = 0; i < 8; ++i) {
        int lin = i * 256 + tid;  // 2048 float4 loads, coalesced in 128B runs
        int r = lin >> 3;
        int c4 = lin & 7;
        int m = m0 + r;
        float4 v = make_float4(0.f, 0.f, 0.f, 0.f);
        if (m < M) v = *(const float4*)(Ap + (size_t)m * H + kc + c4 * 4);
        int c = c4 * 4;
        sA[(c + 0) * 260 + r] = v.x;
        sA[(c + 1) * 260 + r] = v.y;
        sA[(c + 2) * 260 + r] = v.z;
        sA[(c + 3) * 260 + r] = v.w;
      }
      __syncthreads();
#pragma unroll 4
      for (int k = 0; k < 32; ++k) {
        float a = sA[k * 260 + tid];
        const float* w = Wp + (size_t)(kc + k) * H + jb;  // wave-uniform
#pragma unroll
        for (int j = 0; j < 64; ++j) acc[j] = fmaf(a, w[j], acc[j]);
      }
    }
  }
  int m = m0 + tid;
  if (m < M) {
    float* op = out + (size_t)m * H + jb;
#pragma unroll
    for (int j4 = 0; j4 < 16; ++j4) {
      float4 v;
      v.x = fmaxf(acc[j4 * 4 + 0] + br[jb + j4 * 4 + 0], 0.f);
      v.y = fmaxf(acc[j4 * 4 + 1] + br[jb + j4 * 4 + 1], 0.f);
      v.z = fmaxf(acc[j4 * 4 + 2] + br[jb + j4 * 4 + 2], 0.f);
      v.w = fmaxf(acc[j4 * 4 + 3] + br[jb + j4 * 4 + 3], 0.f);
      *(float4*)(op + j4 * 4) = v;
    }
  }
}

// ---------------- pooling + head ----------------
__global__ void k_bounds(const int* __restrict__ batch, int* __restrict__ gstart) {
  int g = threadIdx.x;
  if (g > NG) return;
  int lo = 0, hi = NN;
  while (lo < hi) {
    int mid = (lo + hi) >> 1;
    if (batch[mid] < g) lo = mid + 1; else hi = mid;
  }
  gstart[g] = lo;
}

// Tiled pooling: 782 blocks x 128 nodes each; thread j owns column j.
// batch is sorted -> run-length accumulate locally, atomicAdd on run boundary.
// (R1 fix: old one-block-per-graph k_pool was 198 us at 2.6% occupancy.)
#define POOL_TILE 128
__global__ void k_pool2(const float* __restrict__ x, const int* __restrict__ batch,
                        float* __restrict__ gsum) {
  int n0 = blockIdx.x * POOL_TILE;
  int j = threadIdx.x;
  int end = n0 + POOL_TILE;
  if (end > NN) end = NN;
  if (n0 >= NN) return;
  int cur_g = batch[n0];
  float acc = 0.f;
  for (int i = n0; i < end; ++i) {
    int g = batch[i];  // wave-uniform load, cache-broadcast
    if (g != cur_g) {
      atomicAdd(&gsum[cur_g * H + j], acc);
      acc = 0.f;
      cur_g = g;
    }
    acc += x[(size_t)i * H + j];
  }
  atomicAdd(&gsum[cur_g * H + j], acc);
}

__global__ void k_head(const float* __restrict__ gsum, const int* __restrict__ gstart,
                       const float* __restrict__ W5, const float* __restrict__ b5,
                       const float* __restrict__ W6, const float* __restrict__ b6,
                       const float* __restrict__ W7, const float* __restrict__ b7,
                       const float* __restrict__ W8, const float* __restrict__ b8,
                       const float* __restrict__ Wl, const float* __restrict__ bl,
                       float* __restrict__ out) {
  __shared__ float s0[128], s1[128];
  const int g = blockIdx.x, j = threadIdx.x;
  float cnt = (float)(gstart[g + 1] - gstart[g]);
  s0[j] = gsum[g * 128 + j] / fmaxf(cnt, 1.f);
  __syncthreads();
  const float* Ws[4] = {W5, W6, W7, W8};
  const float* bs[4] = {b5, b6, b7, b8};
  float* cur = s0;
  float* nxt = s1;
  for (int L = 0; L < 4; ++L) {
    const float* W = Ws[L];
    float a = bs[L][j];
    for (int k = 0; k < 128; ++k) a = fmaf(cur[k], W[k * 128 + j], a);
    nxt[j] = fmaxf(a, 0.f);
    __syncthreads();
    float* t = cur; cur = nxt; nxt = t;
  }
  if (j < 2) {
    float a = bl[j];
    for (int k = 0; k < 128; ++k) a = fmaf(cur[k], Wl[k * 2 + j], a);
    out[g * 2 + j] = 1.f / (1.f + __expf(-a));
  }
}

// ---------------- launch ----------------
static inline char* ws_take(char*& p, size_t bytes) {
  char* r = p;
  p += (bytes + 255) & ~(size_t)255;
  return r;
}

extern "C" void kernel_launch(void* const* d_in, const int* in_sizes, int n_in,
                              void* d_out, int out_size, void* d_ws, size_t ws_size,
                              hipStream_t stream) {
  const float* x0 = (const float*)d_in[0];
  const int* ei = (const int*)d_in[1];
  const int* batch = (const int*)d_in[2];
  const float* Wr[4] = {(const float*)d_in[3], (const float*)d_in[6],
                        (const float*)d_in[9], (const float*)d_in[12]};
  const float* brr[4] = {(const float*)d_in[4], (const float*)d_in[7],
                         (const float*)d_in[10], (const float*)d_in[13]};
  const float* Wo[4] = {(const float*)d_in[5], (const float*)d_in[8],
                        (const float*)d_in[11], (const float*)d_in[14]};
  const float* W5 = (const float*)d_in[15];
  const float* b5 = (const float*)d_in[16];
  const float* W6 = (const float*)d_in[17];
  const float* b6 = (const float*)d_in[18];
  const float* W7 = (const float*)d_in[19];
  const float* b7 = (const float*)d_in[20];
  const float* W8 = (const float*)d_in[21];
  const float* b8 = (const float*)d_in[22];
  const float* Wl = (const float*)d_in[23];
  const float* bl = (const float*)d_in[24];
  float* out = (float*)d_out;

  char* p = (char*)d_ws;
  int* fillptr = (int*)ws_take(p, (size_t)NN * 4);
  int* rowptr = (int*)ws_take(p, (size_t)(NN + 1) * 4);
  int* bsums = (int*)ws_take(p, 1024 * 4);
  int* gstart = (int*)ws_take(p, (NG + 1) * 4);
  int* col = (int*)ws_take(p, (size_t)NE * 4);
  float* agg = (float*)ws_take(p, (size_t)NN * H * 4);
  float* bufA = (float*)ws_take(p, (size_t)NN * H * 4);
  float* bufB = (float*)ws_take(p, (size_t)NN * H * 4);
  float* gsum = (float*)ws_take(p, (size_t)NG * H * 4);
  (void)ws_size; (void)in_sizes; (void)n_in; (void)out_size;

  hipMemsetAsync(fillptr, 0, (size_t)NN * 4, stream);
  hipMemsetAsync(gsum, 0, (size_t)NG * H * 4, stream);
  k_hist<<<(NE + 255) / 256, 256, 0, stream>>>(ei, fillptr);
  k_scan1<<<SCAN_GRID, SCAN_B, 0, stream>>>(fillptr, rowptr + 1, bsums);
  k_scan2<<<1, 128, 0, stream>>>(bsums);
  k_scan3<<<SCAN_GRID, SCAN_B, 0, stream>>>(rowptr, bsums, fillptr);
  k_fill<<<(NE + 255) / 256, 256, 0, stream>>>(ei, fillptr, col);

  // layer 1 (F_IN=4): aggregate in input space, then small GEMM
  k_agg4<<<(NN + 255) / 256, 256, 0, stream>>>(x0, rowptr, col, agg);
  k_gemm4<<<NN / 2, 256, 0, stream>>>(agg, x0, Wr[0], Wo[0], brr[0], bufA);

  // layers 2-4
  k_agg128<<<25000, 256, 0, stream>>>(bufA, rowptr, col, agg);
  k_gemm128<<<dim3(391, 2), 256, 0, stream>>>(agg, bufA, Wr[1], Wo[1], brr[1], bufB, NN);
  k_agg128<<<25000, 256, 0, stream>>>(bufB, rowptr, col, agg);
  k_gemm128<<<dim3(391, 2), 256, 0, stream>>>(agg, bufB, Wr[2], Wo[2], brr[2], bufA, NN);
  k_agg128<<<25000, 256, 0, stream>>>(bufA, rowptr, col, agg);
  k_gemm128<<<dim3(391, 2), 256, 0, stream>>>(agg, bufA, Wr[3], Wo[3], brr[3], bufB, NN);

  // mean pool + MLP head + sigmoid
  k_bounds<<<1, 256, 0, stream>>>(batch, gstart);
  k_pool2<<<(NN + POOL_TILE - 1) / POOL_TILE, 128, 0, stream>>>(bufB, batch, gsum);
  k_head<<<NG, 128, 0, stream>>>(gsum, gstart, W5, b5, W6, b6, W7, b7, W8, b8, Wl, bl, out);
}

// Round 3
// 841.539 us; speedup vs baseline: 1.5505x; 1.3793x over previous
//
#include <hip/hip_runtime.h>
#include <hip/hip_bf16.h>
#include <math.h>

#define NN 100000
#define NE 1600000
#define NG 128
#define H 128

typedef __attribute__((ext_vector_type(8))) short short8;
typedef __attribute__((ext_vector_type(4))) float floatx4;

// ---------------- CSR build ----------------
__global__ void k_hist(const int* __restrict__ ei, int* __restrict__ cnt) {
  int e = blockIdx.x * blockDim.x + threadIdx.x;
  if (e < NE) atomicAdd(&cnt[ei[NE + e]], 1);
}

#define SCAN_B 1024
#define SCAN_GRID 98  // ceil(100000/1024)

__global__ void k_scan1(const int* __restrict__ cnt, int* __restrict__ rowptr1,
                        int* __restrict__ bsums) {
  __shared__ int s[SCAN_B];
  int tid = threadIdx.x;
  int gid = blockIdx.x * SCAN_B + tid;
  int v = (gid < NN) ? cnt[gid] : 0;
  s[tid] = v;
  __syncthreads();
  for (int off = 1; off < SCAN_B; off <<= 1) {
    int t = (tid >= off) ? s[tid - off] : 0;
    __syncthreads();
    s[tid] += t;
    __syncthreads();
  }
  if (gid < NN) rowptr1[gid] = s[tid];
  if (tid == SCAN_B - 1) bsums[blockIdx.x] = s[tid];
}

__global__ void k_scan2(int* __restrict__ bsums) {
  __shared__ int s[128];
  int tid = threadIdx.x;
  int v = (tid < SCAN_GRID) ? bsums[tid] : 0;
  s[tid] = v;
  __syncthreads();
  for (int off = 1; off < 128; off <<= 1) {
    int t = (tid >= off) ? s[tid - off] : 0;
    __syncthreads();
    s[tid] += t;
    __syncthreads();
  }
  if (tid < SCAN_GRID) bsums[tid] = s[tid];
}

__global__ void k_scan3(int* __restrict__ rowptr, const int* __restrict__ bsums,
                        int* __restrict__ cnt_to_fill) {
  int gid = blockIdx.x * SCAN_B + threadIdx.x;
  if (gid >= NN) return;
  int add = (blockIdx.x > 0) ? bsums[blockIdx.x - 1] : 0;
  int incl = rowptr[gid + 1] + add;
  rowptr[gid + 1] = incl;
  cnt_to_fill[gid] = incl - cnt_to_fill[gid];  // exclusive prefix -> fillptr
  if (gid == 0) rowptr[0] = 0;
}

__global__ void k_fill(const int* __restrict__ ei, int* __restrict__ fillptr,
                       int* __restrict__ col) {
  int e = blockIdx.x * blockDim.x + threadIdx.x;
  if (e >= NE) return;
  int s = ei[e];
  int d = ei[NE + e];
  int pos = atomicAdd(&fillptr[d], 1);
  col[pos] = s;
}

// ---------------- bf16 helpers ----------------
__device__ inline unsigned pk_bf16(float a, float b) {  // RNE pack (lo=a, hi=b)
  unsigned ua = __float_as_uint(a), ub = __float_as_uint(b);
  ua = (ua + 0x7fffu + ((ua >> 16) & 1u)) >> 16;
  ub = (ub + 0x7fffu + ((ub >> 16) & 1u)) & 0xffff0000u;
  return ua | ub;
}

// ---------------- aggregation (bf16 x, fp32 accumulate, bf16 agg) ----------
// one wave per node; lane holds 2 bf16 columns packed in one dword
__global__ void k_aggbf(const unsigned* __restrict__ x, const int* __restrict__ rowptr,
                        const int* __restrict__ col, unsigned* __restrict__ agg) {
  int w = (blockIdx.x * blockDim.x + threadIdx.x) >> 6;
  int lane = threadIdx.x & 63;
  if (w >= NN) return;
  int beg = rowptr[w], end = rowptr[w + 1];
  float a0 = 0.f, a1 = 0.f;
  int e = beg;
  for (; e + 1 < end; e += 2) {  // 2 independent chains to hide gather latency
    int s0 = col[e], s1 = col[e + 1];
    unsigned u0 = x[(size_t)s0 * 64 + lane];
    unsigned u1 = x[(size_t)s1 * 64 + lane];
    a0 += __uint_as_float(u0 << 16) + __uint_as_float(u1 << 16);
    a1 += __uint_as_float(u0 & 0xffff0000u) + __uint_as_float(u1 & 0xffff0000u);
  }
  if (e < end) {
    unsigned u = x[(size_t)col[e] * 64 + lane];
    a0 += __uint_as_float(u << 16);
    a1 += __uint_as_float(u & 0xffff0000u);
  }
  agg[(size_t)w * 64 + lane] = pk_bf16(a0, a1);
}

// layer-1 aggregation in F_IN=4 space (aggregate BEFORE matmul: 25 MB not 819 MB)
__global__ void k_agg4(const float* __restrict__ x, const int* __restrict__ rowptr,
                       const int* __restrict__ col, float* __restrict__ agg4) {
  int i = blockIdx.x * blockDim.x + threadIdx.x;
  if (i >= NN) return;
  int beg = rowptr[i], end = rowptr[i + 1];
  float4 acc = make_float4(0.f, 0.f, 0.f, 0.f);
  for (int e = beg; e < end; ++e) {
    float4 v = ((const float4*)x)[col[e]];
    acc.x += v.x; acc.y += v.y; acc.z += v.z; acc.w += v.w;
  }
  ((float4*)agg4)[i] = acc;
}

// ---------------- layer-1 GEMM (K=4+4), fp32 math, bf16 output -------------
__global__ void k_gemm4(const float* __restrict__ agg4, const float* __restrict__ x4,
                        const float* __restrict__ Wr, const float* __restrict__ Wo,
                        const float* __restrict__ br, __hip_bfloat16* __restrict__ out) {
  __shared__ float sWr[512], sWo[512], sbr[128];
  int tid = threadIdx.x;
  sWr[tid] = Wr[tid]; sWr[tid + 256] = Wr[tid + 256];
  sWo[tid] = Wo[tid]; sWo[tid + 256] = Wo[tid + 256];
  if (tid < 128) sbr[tid] = br[tid];
  __syncthreads();
  int node = blockIdx.x * 2 + (tid >> 7);
  int j = tid & 127;
  if (node >= NN) return;
  float4 a = ((const float4*)agg4)[node];
  float4 xv = ((const float4*)x4)[node];
  float acc = sbr[j];
  acc = fmaf(a.x, sWr[0 * 128 + j], acc);
  acc = fmaf(a.y, sWr[1 * 128 + j], acc);
  acc = fmaf(a.z, sWr[2 * 128 + j], acc);
  acc = fmaf(a.w, sWr[3 * 128 + j], acc);
  acc = fmaf(xv.x, sWo[0 * 128 + j], acc);
  acc = fmaf(xv.y, sWo[1 * 128 + j], acc);
  acc = fmaf(xv.z, sWo[2 * 128 + j], acc);
  acc = fmaf(xv.w, sWo[3 * 128 + j], acc);
  out[(size_t)node * H + j] = __float2bfloat16(fmaxf(acc, 0.f));
}

// ---------------- W -> B-fragment-order bf16 conversion --------------------
// wf[t], t = kt*4096 + n*32 + quad*8 + j  holds  W'[kt*32+quad*8+j][n]
// where W' = [Wr; Wo] (256x128). One thread per element, 32768 total.
__global__ void k_wcvt(const float* __restrict__ Wr, const float* __restrict__ Wo,
                       __hip_bfloat16* __restrict__ wf) {
  int t = blockIdx.x * 256 + threadIdx.x;
  int j = t & 7, quad = (t >> 3) & 3, n = (t >> 5) & 127, kt = t >> 12;
  int r = kt * 32 + quad * 8 + j;
  float v = (r < 128) ? Wr[r * 128 + n] : Wo[(r - 128) * 128 + n];
  wf[t] = __float2bfloat16(v);
}

// ---------------- MFMA GEMM: relu([agg|x] @ [Wr;Wo] + br) ------------------
// 4 waves x 32 rows = 128-row block tile, full N=128. No LDS, no barriers.
// A-frags direct from global (16 rows x 64B contiguous per wave access);
// B-frags from pre-permuted wf (16B/lane contiguous, m92/m97-verified layout).
__global__ __launch_bounds__(256) void k_gemm_mfma(
    const __hip_bfloat16* __restrict__ A, const __hip_bfloat16* __restrict__ X,
    const __hip_bfloat16* __restrict__ Wf, const float* __restrict__ br,
    __hip_bfloat16* __restrict__ out) {
  const int tid = threadIdx.x;
  const int wv = tid >> 6, lane = tid & 63;
  const int quad = lane >> 4, lr = lane & 15;
  const int mbase = blockIdx.x * 128 + wv * 32;

  floatx4 acc[2][8];
#pragma unroll
  for (int rt = 0; rt < 2; ++rt)
#pragma unroll
    for (int ct = 0; ct < 8; ++ct) acc[rt][ct] = (floatx4){0.f, 0.f, 0.f, 0.f};

  int r0 = mbase + lr;      if (r0 > NN - 1) r0 = NN - 1;
  int r1 = mbase + 16 + lr; if (r1 > NN - 1) r1 = NN - 1;

#pragma unroll
  for (int kt = 0; kt < 8; ++kt) {
    const __hip_bfloat16* base = (kt < 4) ? A : X;
    const size_t koff = (size_t)(kt & 3) * 32 + quad * 8;
    short8 a0 = *(const short8*)(base + (size_t)r0 * H + koff);
    short8 a1 = *(const short8*)(base + (size_t)r1 * H + koff);
    const __hip_bfloat16* wb = Wf + (size_t)kt * 4096 + (size_t)lr * 32 + quad * 8;
#pragma unroll
    for (int ct = 0; ct < 8; ++ct) {
      short8 b = *(const short8*)(wb + ct * 16 * 32);
      acc[0][ct] = __builtin_amdgcn_mfma_f32_16x16x32_bf16(a0, b, acc[0][ct], 0, 0, 0);
      acc[1][ct] = __builtin_amdgcn_mfma_f32_16x16x32_bf16(a1, b, acc[1][ct], 0, 0, 0);
    }
  }

  // C/D layout: col = lane&15, row = quad*4 + reg  [m89-verified]
#pragma unroll
  for (int rt = 0; rt < 2; ++rt) {
    int row0 = mbase + rt * 16 + quad * 4;
#pragma unroll
    for (int ct = 0; ct < 8; ++ct) {
      int n = ct * 16 + lr;
      float bias = br[n];
#pragma unroll
      for (int rg = 0; rg < 4; ++rg) {
        int row = row0 + rg;
        if (row < NN) {
          float v = fmaxf(acc[rt][ct][rg] + bias, 0.f);
          out[(size_t)row * H + n] = __float2bfloat16(v);
        }
      }
    }
  }
}

// ---------------- pooling + head ----------------
__global__ void k_bounds(const int* __restrict__ batch, int* __restrict__ gstart) {
  int g = threadIdx.x;
  if (g > NG) return;
  int lo = 0, hi = NN;
  while (lo < hi) {
    int mid = (lo + hi) >> 1;
    if (batch[mid] < g) lo = mid + 1; else hi = mid;
  }
  gstart[g] = lo;
}

// Tiled pooling over bf16 x: 782 blocks x 128 nodes; thread j owns column j.
#define POOL_TILE 128
__global__ void k_pool2(const __hip_bfloat16* __restrict__ x, const int* __restrict__ batch,
                        float* __restrict__ gsum) {
  int n0 = blockIdx.x * POOL_TILE;
  int j = threadIdx.x;
  int end = n0 + POOL_TILE;
  if (end > NN) end = NN;
  if (n0 >= NN) return;
  int cur_g = batch[n0];
  float acc = 0.f;
  for (int i = n0; i < end; ++i) {
    int g = batch[i];  // wave-uniform load, cache-broadcast
    if (g != cur_g) {
      atomicAdd(&gsum[cur_g * H + j], acc);
      acc = 0.f;
      cur_g = g;
    }
    acc += __bfloat162float(x[(size_t)i * H + j]);
  }
  atomicAdd(&gsum[cur_g * H + j], acc);
}

__global__ void k_head(const float* __restrict__ gsum, const int* __restrict__ gstart,
                       const float* __restrict__ W5, const float* __restrict__ b5,
                       const float* __restrict__ W6, const float* __restrict__ b6,
                       const float* __restrict__ W7, const float* __restrict__ b7,
                       const float* __restrict__ W8, const float* __restrict__ b8,
                       const float* __restrict__ Wl, const float* __restrict__ bl,
                       float* __restrict__ out) {
  __shared__ float s0[128], s1[128];
  const int g = blockIdx.x, j = threadIdx.x;
  float cnt = (float)(gstart[g + 1] - gstart[g]);
  s0[j] = gsum[g * 128 + j] / fmaxf(cnt, 1.f);
  __syncthreads();
  const float* Ws[4] = {W5, W6, W7, W8};
  const float* bs[4] = {b5, b6, b7, b8};
  float* cur = s0;
  float* nxt = s1;
  for (int L = 0; L < 4; ++L) {
    const float* W = Ws[L];
    float a = bs[L][j];
    for (int k = 0; k < 128; ++k) a = fmaf(cur[k], W[k * 128 + j], a);
    nxt[j] = fmaxf(a, 0.f);
    __syncthreads();
    float* t = cur; cur = nxt; nxt = t;
  }
  if (j < 2) {
    float a = bl[j];
    for (int k = 0; k < 128; ++k) a = fmaf(cur[k], Wl[k * 2 + j], a);
    out[g * 2 + j] = 1.f / (1.f + __expf(-a));
  }
}

// ---------------- launch ----------------
static inline char* ws_take(char*& p, size_t bytes) {
  char* r = p;
  p += (bytes + 255) & ~(size_t)255;
  return r;
}

extern "C" void kernel_launch(void* const* d_in, const int* in_sizes, int n_in,
                              void* d_out, int out_size, void* d_ws, size_t ws_size,
                              hipStream_t stream) {
  const float* x0 = (const float*)d_in[0];
  const int* ei = (const int*)d_in[1];
  const int* batch = (const int*)d_in[2];
  const float* Wr[4] = {(const float*)d_in[3], (const float*)d_in[6],
                        (const float*)d_in[9], (const float*)d_in[12]};
  const float* brr[4] = {(const float*)d_in[4], (const float*)d_in[7],
                         (const float*)d_in[10], (const float*)d_in[13]};
  const float* Wo[4] = {(const float*)d_in[5], (const float*)d_in[8],
                        (const float*)d_in[11], (const float*)d_in[14]};
  const float* W5 = (const float*)d_in[15];
  const float* b5 = (const float*)d_in[16];
  const float* W6 = (const float*)d_in[17];
  const float* b6 = (const float*)d_in[18];
  const float* W7 = (const float*)d_in[19];
  const float* b7 = (const float*)d_in[20];
  const float* W8 = (const float*)d_in[21];
  const float* b8 = (const float*)d_in[22];
  const float* Wl = (const float*)d_in[23];
  const float* bl = (const float*)d_in[24];
  float* out = (float*)d_out;

  char* p = (char*)d_ws;
  int* fillptr = (int*)ws_take(p, (size_t)NN * 4);
  int* rowptr = (int*)ws_take(p, (size_t)(NN + 1) * 4);
  int* bsums = (int*)ws_take(p, 1024 * 4);
  int* gstart = (int*)ws_take(p, (NG + 1) * 4);
  int* col = (int*)ws_take(p, (size_t)NE * 4);
  __hip_bfloat16* agg = (__hip_bfloat16*)ws_take(p, (size_t)NN * H * 2);
  __hip_bfloat16* bufA = (__hip_bfloat16*)ws_take(p, (size_t)NN * H * 2);
  __hip_bfloat16* bufB = (__hip_bfloat16*)ws_take(p, (size_t)NN * H * 2);
  float* agg4 = (float*)ws_take(p, (size_t)NN * 4 * 4);
  float* gsum = (float*)ws_take(p, (size_t)NG * H * 4);
  __hip_bfloat16* wf1 = (__hip_bfloat16*)ws_take(p, 32768 * 2);
  __hip_bfloat16* wf2 = (__hip_bfloat16*)ws_take(p, 32768 * 2);
  __hip_bfloat16* wf3 = (__hip_bfloat16*)ws_take(p, 32768 * 2);
  (void)ws_size; (void)in_sizes; (void)n_in; (void)out_size;

  hipMemsetAsync(fillptr, 0, (size_t)NN * 4, stream);
  hipMemsetAsync(gsum, 0, (size_t)NG * H * 4, stream);
  k_hist<<<(NE + 255) / 256, 256, 0, stream>>>(ei, fillptr);
  k_wcvt<<<128, 256, 0, stream>>>(Wr[1], Wo[1], wf1);
  k_wcvt<<<128, 256, 0, stream>>>(Wr[2], Wo[2], wf2);
  k_wcvt<<<128, 256, 0, stream>>>(Wr[3], Wo[3], wf3);
  k_scan1<<<SCAN_GRID, SCAN_B, 0, stream>>>(fillptr, rowptr + 1, bsums);
  k_scan2<<<1, 128, 0, stream>>>(bsums);
  k_scan3<<<SCAN_GRID, SCAN_B, 0, stream>>>(rowptr, bsums, fillptr);
  k_fill<<<(NE + 255) / 256, 256, 0, stream>>>(ei, fillptr, col);

  // layer 1 (F_IN=4): aggregate in input space, then small GEMM -> bf16
  k_agg4<<<(NN + 255) / 256, 256, 0, stream>>>(x0, rowptr, col, agg4);
  k_gemm4<<<NN / 2, 256, 0, stream>>>(agg4, x0, Wr[0], Wo[0], brr[0], bufA);

  // layers 2-4: bf16 gather-agg + MFMA GEMM
  k_aggbf<<<25000, 256, 0, stream>>>((const unsigned*)bufA, rowptr, col, (unsigned*)agg);
  k_gemm_mfma<<<782, 256, 0, stream>>>(agg, bufA, wf1, brr[1], bufB);
  k_aggbf<<<25000, 256, 0, stream>>>((const unsigned*)bufB, rowptr, col, (unsigned*)agg);
  k_gemm_mfma<<<782, 256, 0, stream>>>(agg, bufB, wf2, brr[2], bufA);
  k_aggbf<<<25000, 256, 0, stream>>>((const unsigned*)bufA, rowptr, col, (unsigned*)agg);
  k_gemm_mfma<<<782, 256, 0, stream>>>(agg, bufA, wf3, brr[3], bufB);

  // mean pool + MLP head + sigmoid
  k_bounds<<<1, 256, 0, stream>>>(batch, gstart);
  k_pool2<<<(NN + POOL_TILE - 1) / POOL_TILE, 128, 0, stream>>>(bufB, batch, gsum);
  k_head<<<NG, 128, 0, stream>>>(gsum, gstart, W5, b5, W6, b6, W7, b7, W8, b8, Wl, bl, out);
}

// Round 4
// 796.719 us; speedup vs baseline: 1.6377x; 1.0563x over previous
//
#include <hip/hip_runtime.h>
#include <hip/hip_bf16.h>
#include <math.h>

#define NN 100000
#define NE 1600000
#define NG 128
#define H 128
#define RANGE 12500  // NN/8 : dst-range per XCD group

typedef __attribute__((ext_vector_type(8))) short short8;
typedef __attribute__((ext_vector_type(4))) float floatx4;

// ---------------- CSR build (XCD-range-partitioned) ----------------
// blockIdx&7 pins the block's dst-range to one XCD (round-robin dispatch
// heuristic); atomics + col writes confined to <1 MB -> stay in that XCD's L2.
// Costs 8x coalesced dst re-read (51 MB, ~9us) to kill 100 MB scatter-write
// amplification (R3: k_fill WRITE_SIZE was 106 MB for a 6.4 MB array).
__global__ void k_hist2(const int* __restrict__ ei, int* __restrict__ cnt) {
  int g = blockIdx.x & 7;
  int j = blockIdx.x >> 3;  // 0..127
  int lo = g * RANGE, hi = lo + RANGE;
  const int* dst = ei + NE;
  for (int e = j * 256 + threadIdx.x; e < NE; e += 128 * 256) {
    int d = dst[e];
    if (d >= lo && d < hi) atomicAdd(&cnt[d], 1);
  }
}

__global__ void k_fill2(const int* __restrict__ ei, int* __restrict__ fillptr,
                        int* __restrict__ col) {
  int g = blockIdx.x & 7;
  int j = blockIdx.x >> 3;
  int lo = g * RANGE, hi = lo + RANGE;
  const int* dst = ei + NE;
  for (int e = j * 256 + threadIdx.x; e < NE; e += 128 * 256) {
    int d = dst[e];
    if (d >= lo && d < hi) {
      int s = ei[e];
      int pos = atomicAdd(&fillptr[d], 1);
      col[pos] = s;
    }
  }
}

#define SCAN_B 1024
#define SCAN_GRID 98  // ceil(100000/1024)

__global__ void k_scan1(const int* __restrict__ cnt, int* __restrict__ rowptr1,
                        int* __restrict__ bsums) {
  __shared__ int s[SCAN_B];
  int tid = threadIdx.x;
  int gid = blockIdx.x * SCAN_B + tid;
  int v = (gid < NN) ? cnt[gid] : 0;
  s[tid] = v;
  __syncthreads();
  for (int off = 1; off < SCAN_B; off <<= 1) {
    int t = (tid >= off) ? s[tid - off] : 0;
    __syncthreads();
    s[tid] += t;
    __syncthreads();
  }
  if (gid < NN) rowptr1[gid] = s[tid];
  if (tid == SCAN_B - 1) bsums[blockIdx.x] = s[tid];
}

__global__ void k_scan2(int* __restrict__ bsums) {
  __shared__ int s[128];
  int tid = threadIdx.x;
  int v = (tid < SCAN_GRID) ? bsums[tid] : 0;
  s[tid] = v;
  __syncthreads();
  for (int off = 1; off < 128; off <<= 1) {
    int t = (tid >= off) ? s[tid - off] : 0;
    __syncthreads();
    s[tid] += t;
    __syncthreads();
  }
  if (tid < SCAN_GRID) bsums[tid] = s[tid];
}

__global__ void k_scan3(int* __restrict__ rowptr, const int* __restrict__ bsums,
                        int* __restrict__ cnt_to_fill) {
  int gid = blockIdx.x * SCAN_B + threadIdx.x;
  if (gid >= NN) return;
  int add = (blockIdx.x > 0) ? bsums[blockIdx.x - 1] : 0;
  int incl = rowptr[gid + 1] + add;
  rowptr[gid + 1] = incl;
  cnt_to_fill[gid] = incl - cnt_to_fill[gid];  // exclusive prefix -> fillptr
  if (gid == 0) rowptr[0] = 0;
}

// ---------------- bf16 helpers ----------------
__device__ inline unsigned pk_bf16(float a, float b) {  // RNE pack (lo=a, hi=b)
  unsigned ua = __float_as_uint(a), ub = __float_as_uint(b);
  ua = (ua + 0x7fffu + ((ua >> 16) & 1u)) >> 16;
  ub = (ub + 0x7fffu + ((ub >> 16) & 1u)) & 0xffff0000u;
  return ua | ub;
}

// ---------------- aggregation (bf16 x, fp32 accumulate, bf16 agg) ----------
// one wave per node; lane holds 2 bf16 columns packed in one dword
__global__ void k_aggbf(const unsigned* __restrict__ x, const int* __restrict__ rowptr,
                        const int* __restrict__ col, unsigned* __restrict__ agg) {
  int w = (blockIdx.x * blockDim.x + threadIdx.x) >> 6;
  int lane = threadIdx.x & 63;
  if (w >= NN) return;
  int beg = rowptr[w], end = rowptr[w + 1];
  float a0 = 0.f, a1 = 0.f;
  int e = beg;
  for (; e + 1 < end; e += 2) {  // 2 independent chains to hide gather latency
    int s0 = col[e], s1 = col[e + 1];
    unsigned u0 = x[(size_t)s0 * 64 + lane];
    unsigned u1 = x[(size_t)s1 * 64 + lane];
    a0 += __uint_as_float(u0 << 16) + __uint_as_float(u1 << 16);
    a1 += __uint_as_float(u0 & 0xffff0000u) + __uint_as_float(u1 & 0xffff0000u);
  }
  if (e < end) {
    unsigned u = x[(size_t)col[e] * 64 + lane];
    a0 += __uint_as_float(u << 16);
    a1 += __uint_as_float(u & 0xffff0000u);
  }
  agg[(size_t)w * 64 + lane] = pk_bf16(a0, a1);
}

// layer-1 aggregation in F_IN=4 space (aggregate BEFORE matmul: 25 MB not 819 MB)
__global__ void k_agg4(const float* __restrict__ x, const int* __restrict__ rowptr,
                       const int* __restrict__ col, float* __restrict__ agg4) {
  int i = blockIdx.x * blockDim.x + threadIdx.x;
  if (i >= NN) return;
  int beg = rowptr[i], end = rowptr[i + 1];
  float4 acc = make_float4(0.f, 0.f, 0.f, 0.f);
  for (int e = beg; e < end; ++e) {
    float4 v = ((const float4*)x)[col[e]];
    acc.x += v.x; acc.y += v.y; acc.z += v.z; acc.w += v.w;
  }
  ((float4*)agg4)[i] = acc;
}

// ---------------- layer-1 GEMM (K=4+4), fp32 math, bf16 output -------------
__global__ void k_gemm4(const float* __restrict__ agg4, const float* __restrict__ x4,
                        const float* __restrict__ Wr, const float* __restrict__ Wo,
                        const float* __restrict__ br, __hip_bfloat16* __restrict__ out) {
  __shared__ float sWr[512], sWo[512], sbr[128];
  int tid = threadIdx.x;
  sWr[tid] = Wr[tid]; sWr[tid + 256] = Wr[tid + 256];
  sWo[tid] = Wo[tid]; sWo[tid + 256] = Wo[tid + 256];
  if (tid < 128) sbr[tid] = br[tid];
  __syncthreads();
  int node = blockIdx.x * 2 + (tid >> 7);
  int j = tid & 127;
  if (node >= NN) return;
  float4 a = ((const float4*)agg4)[node];
  float4 xv = ((const float4*)x4)[node];
  float acc = sbr[j];
  acc = fmaf(a.x, sWr[0 * 128 + j], acc);
  acc = fmaf(a.y, sWr[1 * 128 + j], acc);
  acc = fmaf(a.z, sWr[2 * 128 + j], acc);
  acc = fmaf(a.w, sWr[3 * 128 + j], acc);
  acc = fmaf(xv.x, sWo[0 * 128 + j], acc);
  acc = fmaf(xv.y, sWo[1 * 128 + j], acc);
  acc = fmaf(xv.z, sWo[2 * 128 + j], acc);
  acc = fmaf(xv.w, sWo[3 * 128 + j], acc);
  out[(size_t)node * H + j] = __float2bfloat16(fmaxf(acc, 0.f));
}

// ---------------- W -> B-fragment-order bf16 conversion --------------------
// wf[t], t = kt*4096 + n*32 + quad*8 + j  holds  W'[kt*32+quad*8+j][n]
// where W' = [Wr; Wo] (256x128). One thread per element, 32768 total.
__global__ void k_wcvt(const float* __restrict__ Wr, const float* __restrict__ Wo,
                       __hip_bfloat16* __restrict__ wf) {
  int t = blockIdx.x * 256 + threadIdx.x;
  int j = t & 7, quad = (t >> 3) & 3, n = (t >> 5) & 127, kt = t >> 12;
  int r = kt * 32 + quad * 8 + j;
  float v = (r < 128) ? Wr[r * 128 + n] : Wo[(r - 128) * 128 + n];
  wf[t] = __float2bfloat16(v);
}

// ---------------- MFMA GEMM: relu([agg|x] @ [Wr;Wo] + br) ------------------
// 4 waves x 32 rows = 128-row block tile, full N=128. No LDS, no barriers.
// A-frags direct from global (16 rows x 64B contiguous per wave access);
// B-frags from pre-permuted wf (16B/lane contiguous, m92/m97-verified layout).
__global__ __launch_bounds__(256) void k_gemm_mfma(
    const __hip_bfloat16* __restrict__ A, const __hip_bfloat16* __restrict__ X,
    const __hip_bfloat16* __restrict__ Wf, const float* __restrict__ br,
    __hip_bfloat16* __restrict__ out) {
  const int tid = threadIdx.x;
  const int wv = tid >> 6, lane = tid & 63;
  const int quad = lane >> 4, lr = lane & 15;
  const int mbase = blockIdx.x * 128 + wv * 32;

  floatx4 acc[2][8];
#pragma unroll
  for (int rt = 0; rt < 2; ++rt)
#pragma unroll
    for (int ct = 0; ct < 8; ++ct) acc[rt][ct] = (floatx4){0.f, 0.f, 0.f, 0.f};

  int r0 = mbase + lr;      if (r0 > NN - 1) r0 = NN - 1;
  int r1 = mbase + 16 + lr; if (r1 > NN - 1) r1 = NN - 1;

#pragma unroll
  for (int kt = 0; kt < 8; ++kt) {
    const __hip_bfloat16* base = (kt < 4) ? A : X;
    const size_t koff = (size_t)(kt & 3) * 32 + quad * 8;
    short8 a0 = *(const short8*)(base + (size_t)r0 * H + koff);
    short8 a1 = *(const short8*)(base + (size_t)r1 * H + koff);
    const __hip_bfloat16* wb = Wf + (size_t)kt * 4096 + (size_t)lr * 32 + quad * 8;
#pragma unroll
    for (int ct = 0; ct < 8; ++ct) {
      short8 b = *(const short8*)(wb + ct * 16 * 32);
      acc[0][ct] = __builtin_amdgcn_mfma_f32_16x16x32_bf16(a0, b, acc[0][ct], 0, 0, 0);
      acc[1][ct] = __builtin_amdgcn_mfma_f32_16x16x32_bf16(a1, b, acc[1][ct], 0, 0, 0);
    }
  }

  // C/D layout: col = lane&15, row = quad*4 + reg  [m89-verified]
#pragma unroll
  for (int rt = 0; rt < 2; ++rt) {
    int row0 = mbase + rt * 16 + quad * 4;
#pragma unroll
    for (int ct = 0; ct < 8; ++ct) {
      int n = ct * 16 + lr;
      float bias = br[n];
#pragma unroll
      for (int rg = 0; rg < 4; ++rg) {
        int row = row0 + rg;
        if (row < NN) {
          float v = fmaxf(acc[rt][ct][rg] + bias, 0.f);
          out[(size_t)row * H + n] = __float2bfloat16(v);
        }
      }
    }
  }
}

// ---------------- pooling + head ----------------
__global__ void k_bounds(const int* __restrict__ batch, int* __restrict__ gstart) {
  int g = threadIdx.x;
  if (g > NG) return;
  int lo = 0, hi = NN;
  while (lo < hi) {
    int mid = (lo + hi) >> 1;
    if (batch[mid] < g) lo = mid + 1; else hi = mid;
  }
  gstart[g] = lo;
}

// Tiled pooling over bf16 x: 782 blocks x 128 nodes; thread j owns column j.
#define POOL_TILE 128
__global__ void k_pool2(const __hip_bfloat16* __restrict__ x, const int* __restrict__ batch,
                        float* __restrict__ gsum) {
  int n0 = blockIdx.x * POOL_TILE;
  int j = threadIdx.x;
  int end = n0 + POOL_TILE;
  if (end > NN) end = NN;
  if (n0 >= NN) return;
  int cur_g = batch[n0];
  float acc = 0.f;
  for (int i = n0; i < end; ++i) {
    int g = batch[i];  // wave-uniform load, cache-broadcast
    if (g != cur_g) {
      atomicAdd(&gsum[cur_g * H + j], acc);
      acc = 0.f;
      cur_g = g;
    }
    acc += __bfloat162float(x[(size_t)i * H + j]);
  }
  atomicAdd(&gsum[cur_g * H + j], acc);
}

__global__ void k_head(const float* __restrict__ gsum, const int* __restrict__ gstart,
                       const float* __restrict__ W5, const float* __restrict__ b5,
                       const float* __restrict__ W6, const float* __restrict__ b6,
                       const float* __restrict__ W7, const float* __restrict__ b7,
                       const float* __restrict__ W8, const float* __restrict__ b8,
                       const float* __restrict__ Wl, const float* __restrict__ bl,
                       float* __restrict__ out) {
  __shared__ float s0[128], s1[128];
  const int g = blockIdx.x, j = threadIdx.x;
  float cnt = (float)(gstart[g + 1] - gstart[g]);
  s0[j] = gsum[g * 128 + j] / fmaxf(cnt, 1.f);
  __syncthreads();
  const float* Ws[4] = {W5, W6, W7, W8};
  const float* bs[4] = {b5, b6, b7, b8};
  float* cur = s0;
  float* nxt = s1;
  for (int L = 0; L < 4; ++L) {
    const float* W = Ws[L];
    float a = bs[L][j];
    for (int k = 0; k < 128; ++k) a = fmaf(cur[k], W[k * 128 + j], a);
    nxt[j] = fmaxf(a, 0.f);
    __syncthreads();
    float* t = cur; cur = nxt; nxt = t;
  }
  if (j < 2) {
    float a = bl[j];
    for (int k = 0; k < 128; ++k) a = fmaf(cur[k], Wl[k * 2 + j], a);
    out[g * 2 + j] = 1.f / (1.f + __expf(-a));
  }
}

// ---------------- launch ----------------
static inline char* ws_take(char*& p, size_t bytes) {
  char* r = p;
  p += (bytes + 255) & ~(size_t)255;
  return r;
}

extern "C" void kernel_launch(void* const* d_in, const int* in_sizes, int n_in,
                              void* d_out, int out_size, void* d_ws, size_t ws_size,
                              hipStream_t stream) {
  const float* x0 = (const float*)d_in[0];
  const int* ei = (const int*)d_in[1];
  const int* batch = (const int*)d_in[2];
  const float* Wr[4] = {(const float*)d_in[3], (const float*)d_in[6],
                        (const float*)d_in[9], (const float*)d_in[12]};
  const float* brr[4] = {(const float*)d_in[4], (const float*)d_in[7],
                         (const float*)d_in[10], (const float*)d_in[13]};
  const float* Wo[4] = {(const float*)d_in[5], (const float*)d_in[8],
                        (const float*)d_in[11], (const float*)d_in[14]};
  const float* W5 = (const float*)d_in[15];
  const float* b5 = (const float*)d_in[16];
  const float* W6 = (const float*)d_in[17];
  const float* b6 = (const float*)d_in[18];
  const float* W7 = (const float*)d_in[19];
  const float* b7 = (const float*)d_in[20];
  const float* W8 = (const float*)d_in[21];
  const float* b8 = (const float*)d_in[22];
  const float* Wl = (const float*)d_in[23];
  const float* bl = (const float*)d_in[24];
  float* out = (float*)d_out;

  char* p = (char*)d_ws;
  int* fillptr = (int*)ws_take(p, (size_t)NN * 4);
  int* rowptr = (int*)ws_take(p, (size_t)(NN + 1) * 4);
  int* bsums = (int*)ws_take(p, 1024 * 4);
  int* gstart = (int*)ws_take(p, (NG + 1) * 4);
  int* col = (int*)ws_take(p, (size_t)NE * 4);
  __hip_bfloat16* agg = (__hip_bfloat16*)ws_take(p, (size_t)NN * H * 2);
  __hip_bfloat16* bufA = (__hip_bfloat16*)ws_take(p, (size_t)NN * H * 2);
  __hip_bfloat16* bufB = (__hip_bfloat16*)ws_take(p, (size_t)NN * H * 2);
  float* agg4 = (float*)ws_take(p, (size_t)NN * 4 * 4);
  float* gsum = (float*)ws_take(p, (size_t)NG * H * 4);
  __hip_bfloat16* wf1 = (__hip_bfloat16*)ws_take(p, 32768 * 2);
  __hip_bfloat16* wf2 = (__hip_bfloat16*)ws_take(p, 32768 * 2);
  __hip_bfloat16* wf3 = (__hip_bfloat16*)ws_take(p, 32768 * 2);
  (void)ws_size; (void)in_sizes; (void)n_in; (void)out_size;

  hipMemsetAsync(fillptr, 0, (size_t)NN * 4, stream);
  hipMemsetAsync(gsum, 0, (size_t)NG * H * 4, stream);
  k_hist2<<<1024, 256, 0, stream>>>(ei, fillptr);
  k_wcvt<<<128, 256, 0, stream>>>(Wr[1], Wo[1], wf1);
  k_wcvt<<<128, 256, 0, stream>>>(Wr[2], Wo[2], wf2);
  k_wcvt<<<128, 256, 0, stream>>>(Wr[3], Wo[3], wf3);
  k_scan1<<<SCAN_GRID, SCAN_B, 0, stream>>>(fillptr, rowptr + 1, bsums);
  k_scan2<<<1, 128, 0, stream>>>(bsums);
  k_scan3<<<SCAN_GRID, SCAN_B, 0, stream>>>(rowptr, bsums, fillptr);
  k_fill2<<<1024, 256, 0, stream>>>(ei, fillptr, col);

  // layer 1 (F_IN=4): aggregate in input space, then small GEMM -> bf16
  k_agg4<<<(NN + 255) / 256, 256, 0, stream>>>(x0, rowptr, col, agg4);
  k_gemm4<<<NN / 2, 256, 0, stream>>>(agg4, x0, Wr[0], Wo[0], brr[0], bufA);

  // layers 2-4: bf16 gather-agg + MFMA GEMM
  k_aggbf<<<25000, 256, 0, stream>>>((const unsigned*)bufA, rowptr, col, (unsigned*)agg);
  k_gemm_mfma<<<782, 256, 0, stream>>>(agg, bufA, wf1, brr[1], bufB);
  k_aggbf<<<25000, 256, 0, stream>>>((const unsigned*)bufB, rowptr, col, (unsigned*)agg);
  k_gemm_mfma<<<782, 256, 0, stream>>>(agg, bufB, wf2, brr[2], bufA);
  k_aggbf<<<25000, 256, 0, stream>>>((const unsigned*)bufA, rowptr, col, (unsigned*)agg);
  k_gemm_mfma<<<782, 256, 0, stream>>>(agg, bufA, wf3, brr[3], bufB);

  // mean pool + MLP head + sigmoid
  k_bounds<<<1, 256, 0, stream>>>(batch, gstart);
  k_pool2<<<(NN + POOL_TILE - 1) / POOL_TILE, 128, 0, stream>>>(bufB, batch, gsum);
  k_head<<<NG, 128, 0, stream>>>(gsum, gstart, W5, b5, W6, b6, W7, b7, W8, b8, Wl, bl, out);
}

// Round 5
// 605.714 us; speedup vs baseline: 2.1541x; 1.3153x over previous
//
#include <hip/hip_runtime.h>
#include <hip/hip_bf16.h>
#include <math.h>

#define NN 100000
#define NE 1600000
#define NG 128
#define H 128
#define RANGE 12500  // NN/8 : dst-range per XCD group
#define DMAX 64      // padded CSR slots/node; P(deg>64 | Poisson16) ~ 1e-17

typedef __attribute__((ext_vector_type(8))) short short8;
typedef __attribute__((ext_vector_type(4))) float floatx4;

// ---------------- padded-bucket CSR build (no hist, no scan) ---------------
// blockIdx&7 pins each dst-range to one XCD (round-robin heuristic); atomics
// + col writes confined to 3.2 MB -> stay in that XCD's 4 MB L2.
// (R3: unpartitioned fill had 106 MB WRITE_SIZE for a 6.4 MB array.)
__global__ void k_fillpad(const int* __restrict__ ei, int* __restrict__ fcnt,
                          int* __restrict__ colp) {
  int g = blockIdx.x & 7;
  int j = blockIdx.x >> 3;
  int lo = g * RANGE, hi = lo + RANGE;
  const int* dst = ei + NE;
  for (int e = j * 256 + threadIdx.x; e < NE; e += 128 * 256) {
    int d = dst[e];
    if (d >= lo && d < hi) {
      int pos = atomicAdd(&fcnt[d], 1);
      if (pos < DMAX) colp[(d << 6) + pos] = ei[e];
    }
  }
}

// ---------------- bf16 helpers ----------------
__device__ inline unsigned pk_bf16(float a, float b) {  // RNE pack (lo=a, hi=b)
  unsigned ua = __float_as_uint(a), ub = __float_as_uint(b);
  ua = (ua + 0x7fffu + ((ua >> 16) & 1u)) >> 16;
  ub = (ub + 0x7fffu + ((ub >> 16) & 1u)) & 0xffff0000u;
  return ua | ub;
}

__device__ inline float4 bf2x4(uint2 u) {  // 4 packed bf16 -> 4 fp32
  float4 r;
  r.x = __uint_as_float(u.x << 16);
  r.y = __uint_as_float(u.x & 0xffff0000u);
  r.z = __uint_as_float(u.y << 16);
  r.w = __uint_as_float(u.y & 0xffff0000u);
  return r;
}

// ---------------- aggregation (bf16 x, fp32 accumulate, bf16 agg) ----------
// 2 nodes per wave (32 lanes x uint2 = 256 B row each), 4-deep independent
// chains + int4 col loads: ~2 KB outstanding/wave (R4 k_aggbf had ~512 B ->
// Little's-law bound at 4.25 TB/s demand).
__global__ void k_aggbf2(const uint2* __restrict__ xx, const int* __restrict__ fcnt,
                         const int* __restrict__ colp, uint2* __restrict__ agg) {
  int w = (blockIdx.x * blockDim.x + threadIdx.x) >> 6;
  int lane = threadIdx.x & 63;
  int half = lane >> 5, hl = lane & 31;
  int node = 2 * w + half;
  if (node >= NN) return;
  int cnt = fcnt[node];
  if (cnt > DMAX) cnt = DMAX;
  const int* cp = colp + (node << 6);
  float4 ac0 = {0, 0, 0, 0}, ac1 = {0, 0, 0, 0}, ac2 = {0, 0, 0, 0}, ac3 = {0, 0, 0, 0};
  int i = 0;
  for (; i + 3 < cnt; i += 4) {
    int4 ss = *(const int4*)(cp + i);  // 16B-aligned (node*256 + i*4, i%4==0)
    uint2 u0 = xx[(size_t)ss.x * 32 + hl];
    uint2 u1 = xx[(size_t)ss.y * 32 + hl];
    uint2 u2 = xx[(size_t)ss.z * 32 + hl];
    uint2 u3 = xx[(size_t)ss.w * 32 + hl];
    float4 v0 = bf2x4(u0), v1 = bf2x4(u1), v2 = bf2x4(u2), v3 = bf2x4(u3);
    ac0.x += v0.x; ac0.y += v0.y; ac0.z += v0.z; ac0.w += v0.w;
    ac1.x += v1.x; ac1.y += v1.y; ac1.z += v1.z; ac1.w += v1.w;
    ac2.x += v2.x; ac2.y += v2.y; ac2.z += v2.z; ac2.w += v2.w;
    ac3.x += v3.x; ac3.y += v3.y; ac3.z += v3.z; ac3.w += v3.w;
  }
  for (; i < cnt; ++i) {
    float4 v = bf2x4(xx[(size_t)cp[i] * 32 + hl]);
    ac0.x += v.x; ac0.y += v.y; ac0.z += v.z; ac0.w += v.w;
  }
  float sx = ac0.x + ac1.x + ac2.x + ac3.x;
  float sy = ac0.y + ac1.y + ac2.y + ac3.y;
  float sz = ac0.z + ac1.z + ac2.z + ac3.z;
  float sw = ac0.w + ac1.w + ac2.w + ac3.w;
  uint2 o;
  o.x = pk_bf16(sx, sy);
  o.y = pk_bf16(sz, sw);
  agg[(size_t)node * 32 + hl] = o;
}

// layer-1 aggregation in F_IN=4 space: 4 threads/node (4 gather streams),
// shuffle-reduce. (R4 k_agg4 had only 1563 waves = 1.5/SIMD, latency-starved.)
__global__ void k_agg4b(const float* __restrict__ x, const int* __restrict__ fcnt,
                        const int* __restrict__ colp, float* __restrict__ agg4) {
  int t = blockIdx.x * blockDim.x + threadIdx.x;
  int node = t >> 2, q = t & 3;
  if (node >= NN) return;
  int cnt = fcnt[node];
  if (cnt > DMAX) cnt = DMAX;
  const int* cp = colp + (node << 6);
  float4 acc = make_float4(0.f, 0.f, 0.f, 0.f);
  for (int e = q; e < cnt; e += 4) {
    float4 v = ((const float4*)x)[cp[e]];
    acc.x += v.x; acc.y += v.y; acc.z += v.z; acc.w += v.w;
  }
#pragma unroll
  for (int d = 1; d < 4; d <<= 1) {
    acc.x += __shfl_xor(acc.x, d);
    acc.y += __shfl_xor(acc.y, d);
    acc.z += __shfl_xor(acc.z, d);
    acc.w += __shfl_xor(acc.w, d);
  }
  if (q == 0) ((float4*)agg4)[node] = acc;
}

// ---------------- layer-1 GEMM (K=4+4), fp32 math, bf16 output -------------
__global__ void k_gemm4(const float* __restrict__ agg4, const float* __restrict__ x4,
                        const float* __restrict__ Wr, const float* __restrict__ Wo,
                        const float* __restrict__ br, __hip_bfloat16* __restrict__ out) {
  __shared__ float sWr[512], sWo[512], sbr[128];
  int tid = threadIdx.x;
  sWr[tid] = Wr[tid]; sWr[tid + 256] = Wr[tid + 256];
  sWo[tid] = Wo[tid]; sWo[tid + 256] = Wo[tid + 256];
  if (tid < 128) sbr[tid] = br[tid];
  __syncthreads();
  int node = blockIdx.x * 2 + (tid >> 7);
  int j = tid & 127;
  if (node >= NN) return;
  float4 a = ((const float4*)agg4)[node];
  float4 xv = ((const float4*)x4)[node];
  float acc = sbr[j];
  acc = fmaf(a.x, sWr[0 * 128 + j], acc);
  acc = fmaf(a.y, sWr[1 * 128 + j], acc);
  acc = fmaf(a.z, sWr[2 * 128 + j], acc);
  acc = fmaf(a.w, sWr[3 * 128 + j], acc);
  acc = fmaf(xv.x, sWo[0 * 128 + j], acc);
  acc = fmaf(xv.y, sWo[1 * 128 + j], acc);
  acc = fmaf(xv.z, sWo[2 * 128 + j], acc);
  acc = fmaf(xv.w, sWo[3 * 128 + j], acc);
  out[(size_t)node * H + j] = __float2bfloat16(fmaxf(acc, 0.f));
}

// ---------------- W -> B-fragment-order bf16 conversion (all 3 layers) -----
// wf[L][t], t = kt*4096 + n*32 + quad*8 + j  holds  W'[kt*32+quad*8+j][n]
__global__ void k_wcvt3(const float* __restrict__ Wr1, const float* __restrict__ Wo1,
                        const float* __restrict__ Wr2, const float* __restrict__ Wo2,
                        const float* __restrict__ Wr3, const float* __restrict__ Wo3,
                        __hip_bfloat16* __restrict__ wf) {
  int t = blockIdx.x * 256 + threadIdx.x;  // 3*32768 total
  int L = t >> 15, tt = t & 32767;
  const float* Wr = (L == 0) ? Wr1 : (L == 1) ? Wr2 : Wr3;
  const float* Wo = (L == 0) ? Wo1 : (L == 1) ? Wo2 : Wo3;
  int j = tt & 7, quad = (tt >> 3) & 3, n = (tt >> 5) & 127, kt = tt >> 12;
  int r = kt * 32 + quad * 8 + j;
  float v = (r < 128) ? Wr[r * 128 + n] : Wo[(r - 128) * 128 + n];
  wf[t] = __float2bfloat16(v);
}

// ---------------- MFMA GEMM: relu([agg|x] @ [Wr;Wo] + br) ------------------
__global__ __launch_bounds__(256) void k_gemm_mfma(
    const __hip_bfloat16* __restrict__ A, const __hip_bfloat16* __restrict__ X,
    const __hip_bfloat16* __restrict__ Wf, const float* __restrict__ br,
    __hip_bfloat16* __restrict__ out) {
  const int tid = threadIdx.x;
  const int wv = tid >> 6, lane = tid & 63;
  const int quad = lane >> 4, lr = lane & 15;
  const int mbase = blockIdx.x * 128 + wv * 32;

  floatx4 acc[2][8];
#pragma unroll
  for (int rt = 0; rt < 2; ++rt)
#pragma unroll
    for (int ct = 0; ct < 8; ++ct) acc[rt][ct] = (floatx4){0.f, 0.f, 0.f, 0.f};

  int r0 = mbase + lr;      if (r0 > NN - 1) r0 = NN - 1;
  int r1 = mbase + 16 + lr; if (r1 > NN - 1) r1 = NN - 1;

#pragma unroll
  for (int kt = 0; kt < 8; ++kt) {
    const __hip_bfloat16* base = (kt < 4) ? A : X;
    const size_t koff = (size_t)(kt & 3) * 32 + quad * 8;
    short8 a0 = *(const short8*)(base + (size_t)r0 * H + koff);
    short8 a1 = *(const short8*)(base + (size_t)r1 * H + koff);
    const __hip_bfloat16* wb = Wf + (size_t)kt * 4096 + (size_t)lr * 32 + quad * 8;
#pragma unroll
    for (int ct = 0; ct < 8; ++ct) {
      short8 b = *(const short8*)(wb + ct * 16 * 32);
      acc[0][ct] = __builtin_amdgcn_mfma_f32_16x16x32_bf16(a0, b, acc[0][ct], 0, 0, 0);
      acc[1][ct] = __builtin_amdgcn_mfma_f32_16x16x32_bf16(a1, b, acc[1][ct], 0, 0, 0);
    }
  }

  // C/D layout: col = lane&15, row = quad*4 + reg  [m89-verified]
#pragma unroll
  for (int rt = 0; rt < 2; ++rt) {
    int row0 = mbase + rt * 16 + quad * 4;
#pragma unroll
    for (int ct = 0; ct < 8; ++ct) {
      int n = ct * 16 + lr;
      float bias = br[n];
#pragma unroll
      for (int rg = 0; rg < 4; ++rg) {
        int row = row0 + rg;
        if (row < NN) {
          float v = fmaxf(acc[rt][ct][rg] + bias, 0.f);
          out[(size_t)row * H + n] = __float2bfloat16(v);
        }
      }
    }
  }
}

// ---------------- pooling + head ----------------
#define POOL_TILE 128
__global__ void k_pool2(const __hip_bfloat16* __restrict__ x, const int* __restrict__ batch,
                        float* __restrict__ gsum) {
  int n0 = blockIdx.x * POOL_TILE;
  int j = threadIdx.x;
  int end = n0 + POOL_TILE;
  if (end > NN) end = NN;
  if (n0 >= NN) return;
  int cur_g = batch[n0];
  float acc = 0.f;
  for (int i = n0; i < end; ++i) {
    int g = batch[i];  // wave-uniform load, cache-broadcast
    if (g != cur_g) {
      atomicAdd(&gsum[cur_g * H + j], acc);
      acc = 0.f;
      cur_g = g;
    }
    acc += __bfloat162float(x[(size_t)i * H + j]);
  }
  atomicAdd(&gsum[cur_g * H + j], acc);
}

__global__ void k_head2(const float* __restrict__ gsum, const int* __restrict__ batch,
                        const float* __restrict__ W5, const float* __restrict__ b5,
                        const float* __restrict__ W6, const float* __restrict__ b6,
                        const float* __restrict__ W7, const float* __restrict__ b7,
                        const float* __restrict__ W8, const float* __restrict__ b8,
                        const float* __restrict__ Wl, const float* __restrict__ bl,
                        float* __restrict__ out) {
  __shared__ float s0[128], s1[128];
  __shared__ int sb[2];
  const int g = blockIdx.x, j = threadIdx.x;
  if (j < 2) {  // binary search for bounds of graph g (batch sorted)
    int tgt = g + j, lo = 0, hi = NN;
    while (lo < hi) {
      int mid = (lo + hi) >> 1;
      if (batch[mid] < tgt) lo = mid + 1; else hi = mid;
    }
    sb[j] = lo;
  }
  __syncthreads();
  float cnt = (float)(sb[1] - sb[0]);
  s0[j] = gsum[g * 128 + j] / fmaxf(cnt, 1.f);
  __syncthreads();
  const float* Ws[4] = {W5, W6, W7, W8};
  const float* bs[4] = {b5, b6, b7, b8};
  float* cur = s0;
  float* nxt = s1;
  for (int L = 0; L < 4; ++L) {
    const float* W = Ws[L];
    float a = bs[L][j];
    for (int k = 0; k < 128; ++k) a = fmaf(cur[k], W[k * 128 + j], a);
    nxt[j] = fmaxf(a, 0.f);
    __syncthreads();
    float* t = cur; cur = nxt; nxt = t;
  }
  if (j < 2) {
    float a = bl[j];
    for (int k = 0; k < 128; ++k) a = fmaf(cur[k], Wl[k * 2 + j], a);
    out[g * 2 + j] = 1.f / (1.f + __expf(-a));
  }
}

// ---------------- launch ----------------
static inline char* ws_take(char*& p, size_t bytes) {
  char* r = p;
  p += (bytes + 255) & ~(size_t)255;
  return r;
}

extern "C" void kernel_launch(void* const* d_in, const int* in_sizes, int n_in,
                              void* d_out, int out_size, void* d_ws, size_t ws_size,
                              hipStream_t stream) {
  const float* x0 = (const float*)d_in[0];
  const int* ei = (const int*)d_in[1];
  const int* batch = (const int*)d_in[2];
  const float* Wr[4] = {(const float*)d_in[3], (const float*)d_in[6],
                        (const float*)d_in[9], (const float*)d_in[12]};
  const float* brr[4] = {(const float*)d_in[4], (const float*)d_in[7],
                         (const float*)d_in[10], (const float*)d_in[13]};
  const float* Wo[4] = {(const float*)d_in[5], (const float*)d_in[8],
                        (const float*)d_in[11], (const float*)d_in[14]};
  const float* W5 = (const float*)d_in[15];
  const float* b5 = (const float*)d_in[16];
  const float* W6 = (const float*)d_in[17];
  const float* b6 = (const float*)d_in[18];
  const float* W7 = (const float*)d_in[19];
  const float* b7 = (const float*)d_in[20];
  const float* W8 = (const float*)d_in[21];
  const float* b8 = (const float*)d_in[22];
  const float* Wl = (const float*)d_in[23];
  const float* bl = (const float*)d_in[24];
  float* out = (float*)d_out;

  char* p = (char*)d_ws;
  int* fcnt = (int*)ws_take(p, (size_t)NN * 4);
  int* colp = (int*)ws_take(p, (size_t)NN * DMAX * 4);
  __hip_bfloat16* agg = (__hip_bfloat16*)ws_take(p, (size_t)NN * H * 2);
  __hip_bfloat16* bufA = (__hip_bfloat16*)ws_take(p, (size_t)NN * H * 2);
  __hip_bfloat16* bufB = (__hip_bfloat16*)ws_take(p, (size_t)NN * H * 2);
  float* agg4 = (float*)ws_take(p, (size_t)NN * 4 * 4);
  float* gsum = (float*)ws_take(p, (size_t)NG * H * 4);
  __hip_bfloat16* wfall = (__hip_bfloat16*)ws_take(p, 3 * 32768 * 2);
  __hip_bfloat16* wf1 = wfall;
  __hip_bfloat16* wf2 = wfall + 32768;
  __hip_bfloat16* wf3 = wfall + 65536;
  (void)ws_size; (void)in_sizes; (void)n_in; (void)out_size;

  hipMemsetAsync(fcnt, 0, (size_t)NN * 4, stream);
  hipMemsetAsync(gsum, 0, (size_t)NG * H * 4, stream);
  k_wcvt3<<<384, 256, 0, stream>>>(Wr[1], Wo[1], Wr[2], Wo[2], Wr[3], Wo[3], wfall);
  k_fillpad<<<1024, 256, 0, stream>>>(ei, fcnt, colp);

  // layer 1 (F_IN=4): aggregate in input space, then small GEMM -> bf16
  k_agg4b<<<(NN * 4 + 255) / 256, 256, 0, stream>>>(x0, fcnt, colp, agg4);
  k_gemm4<<<NN / 2, 256, 0, stream>>>(agg4, x0, Wr[0], Wo[0], brr[0], bufA);

  // layers 2-4: bf16 gather-agg + MFMA GEMM
  k_aggbf2<<<12500, 256, 0, stream>>>((const uint2*)bufA, fcnt, colp, (uint2*)agg);
  k_gemm_mfma<<<782, 256, 0, stream>>>(agg, bufA, wf1, brr[1], bufB);
  k_aggbf2<<<12500, 256, 0, stream>>>((const uint2*)bufB, fcnt, colp, (uint2*)agg);
  k_gemm_mfma<<<782, 256, 0, stream>>>(agg, bufB, wf2, brr[2], bufA);
  k_aggbf2<<<12500, 256, 0, stream>>>((const uint2*)bufA, fcnt, colp, (uint2*)agg);
  k_gemm_mfma<<<782, 256, 0, stream>>>(agg, bufA, wf3, brr[3], bufB);

  // mean pool + MLP head + sigmoid
  k_pool2<<<(NN + POOL_TILE - 1) / POOL_TILE, 128, 0, stream>>>(bufB, batch, gsum);
  k_head2<<<NG, 128, 0, stream>>>(gsum, batch, W5, b5, W6, b6, W7, b7, W8, b8, Wl, bl, out);
}

// Round 6
// 604.225 us; speedup vs baseline: 2.1595x; 1.0025x over previous
//
#include <hip/hip_runtime.h>
#include <hip/hip_bf16.h>
#include <math.h>

#define NN 100000
#define NE 1600000
#define NG 128
#define H 128
#define RANGE 12500  // NN/8 : dst-range per XCD group
#define DMAX 64      // padded CSR slots/node; P(deg>64 | Poisson16) ~ 1e-17

typedef __attribute__((ext_vector_type(8))) short short8;
typedef __attribute__((ext_vector_type(4))) float floatx4;

// ---------------- padded-bucket CSR build (no hist, no scan) ---------------
// blockIdx&7 pins each dst-range to one XCD; atomics + col writes confined to
// 3.2 MB -> that XCD's L2. R5: serial load->atomic->store chain left atomic
// latency fully exposed (VALUBusy 4%, 82us). Now 4 independent chains/thread.
__global__ void k_fillpad(const int* __restrict__ ei, int* __restrict__ fcnt,
                          int* __restrict__ colp) {
  int g = blockIdx.x & 7;
  int j = blockIdx.x >> 3;  // 0..127
  int lo = g * RANGE, hi = lo + RANGE;
  const int* dst = ei + NE;
  int tid = threadIdx.x;
  for (int base = j * 1024; base < NE; base += 128 * 1024) {
    int e0 = base + tid, e1 = e0 + 256, e2 = e0 + 512, e3 = e0 + 768;
    int d0 = (e0 < NE) ? dst[e0] : -1;
    int d1 = (e1 < NE) ? dst[e1] : -1;
    int d2 = (e2 < NE) ? dst[e2] : -1;
    int d3 = (e3 < NE) ? dst[e3] : -1;
    int s0 = (e0 < NE) ? ei[e0] : 0;
    int s1 = (e1 < NE) ? ei[e1] : 0;
    int s2 = (e2 < NE) ? ei[e2] : 0;
    int s3 = (e3 < NE) ? ei[e3] : 0;
    if (d0 >= lo && d0 < hi) {
      int pos = atomicAdd(&fcnt[d0], 1);
      if (pos < DMAX) colp[(d0 << 6) + pos] = s0;
    }
    if (d1 >= lo && d1 < hi) {
      int pos = atomicAdd(&fcnt[d1], 1);
      if (pos < DMAX) colp[(d1 << 6) + pos] = s1;
    }
    if (d2 >= lo && d2 < hi) {
      int pos = atomicAdd(&fcnt[d2], 1);
      if (pos < DMAX) colp[(d2 << 6) + pos] = s2;
    }
    if (d3 >= lo && d3 < hi) {
      int pos = atomicAdd(&fcnt[d3], 1);
      if (pos < DMAX) colp[(d3 << 6) + pos] = s3;
    }
  }
}

// pad each node's bucket to a multiple of 8 with sentinel NN (a zeroed row in
// bufA/bufB) -> aggbf2 runs a tail-free 8-deep gather loop.
__global__ void k_padtail(const int* __restrict__ fcnt, int* __restrict__ colp) {
  int node = blockIdx.x * 256 + threadIdx.x;
  if (node >= NN) return;
  int cnt = fcnt[node];
  if (cnt > DMAX) cnt = DMAX;
  int up = (cnt + 7) & ~7;
  for (int i = cnt; i < up; ++i) colp[(node << 6) + i] = NN;
}

// ---------------- bf16 helpers ----------------
__device__ inline unsigned pk_bf16(float a, float b) {  // RNE pack (lo=a, hi=b)
  unsigned ua = __float_as_uint(a), ub = __float_as_uint(b);
  ua = (ua + 0x7fffu + ((ua >> 16) & 1u)) >> 16;
  ub = (ub + 0x7fffu + ((ub >> 16) & 1u)) & 0xffff0000u;
  return ua | ub;
}

__device__ inline float4 bf2x4(uint2 u) {  // 4 packed bf16 -> 4 fp32
  float4 r;
  r.x = __uint_as_float(u.x << 16);
  r.y = __uint_as_float(u.x & 0xffff0000u);
  r.z = __uint_as_float(u.y << 16);
  r.w = __uint_as_float(u.y & 0xffff0000u);
  return r;
}

// ---------------- aggregation (bf16 x, fp32 accumulate, bf16 agg) ----------
// 2 nodes/wave (32 lanes x uint2 = 256 B row); 8 gathers in flight, 8
// independent accumulators, NO serial tail (buckets padded to x8 with the
// zero-row sentinel). x must have a zeroed row at index NN.
__global__ void k_aggbf2(const uint2* __restrict__ xx, const int* __restrict__ fcnt,
                         const int* __restrict__ colp, uint2* __restrict__ agg) {
  int w = (blockIdx.x * blockDim.x + threadIdx.x) >> 6;
  int lane = threadIdx.x & 63;
  int half = lane >> 5, hl = lane & 31;
  int node = 2 * w + half;
  if (node >= NN) return;
  int cnt = fcnt[node];
  if (cnt > DMAX) cnt = DMAX;
  cnt = (cnt + 7) & ~7;
  const int* cp = colp + (node << 6);
  float4 ac0 = {0, 0, 0, 0}, ac1 = {0, 0, 0, 0}, ac2 = {0, 0, 0, 0}, ac3 = {0, 0, 0, 0};
  float4 ac4 = {0, 0, 0, 0}, ac5 = {0, 0, 0, 0}, ac6 = {0, 0, 0, 0}, ac7 = {0, 0, 0, 0};
  for (int i = 0; i < cnt; i += 8) {
    int4 sa = *(const int4*)(cp + i);
    int4 sb = *(const int4*)(cp + i + 4);
    uint2 u0 = xx[(size_t)sa.x * 32 + hl];
    uint2 u1 = xx[(size_t)sa.y * 32 + hl];
    uint2 u2 = xx[(size_t)sa.z * 32 + hl];
    uint2 u3 = xx[(size_t)sa.w * 32 + hl];
    uint2 u4 = xx[(size_t)sb.x * 32 + hl];
    uint2 u5 = xx[(size_t)sb.y * 32 + hl];
    uint2 u6 = xx[(size_t)sb.z * 32 + hl];
    uint2 u7 = xx[(size_t)sb.w * 32 + hl];
    float4 v0 = bf2x4(u0), v1 = bf2x4(u1), v2 = bf2x4(u2), v3 = bf2x4(u3);
    float4 v4 = bf2x4(u4), v5 = bf2x4(u5), v6 = bf2x4(u6), v7 = bf2x4(u7);
    ac0.x += v0.x; ac0.y += v0.y; ac0.z += v0.z; ac0.w += v0.w;
    ac1.x += v1.x; ac1.y += v1.y; ac1.z += v1.z; ac1.w += v1.w;
    ac2.x += v2.x; ac2.y += v2.y; ac2.z += v2.z; ac2.w += v2.w;
    ac3.x += v3.x; ac3.y += v3.y; ac3.z += v3.z; ac3.w += v3.w;
    ac4.x += v4.x; ac4.y += v4.y; ac4.z += v4.z; ac4.w += v4.w;
    ac5.x += v5.x; ac5.y += v5.y; ac5.z += v5.z; ac5.w += v5.w;
    ac6.x += v6.x; ac6.y += v6.y; ac6.z += v6.z; ac6.w += v6.w;
    ac7.x += v7.x; ac7.y += v7.y; ac7.z += v7.z; ac7.w += v7.w;
  }
  float sx = (ac0.x + ac1.x) + (ac2.x + ac3.x) + (ac4.x + ac5.x) + (ac6.x + ac7.x);
  float sy = (ac0.y + ac1.y) + (ac2.y + ac3.y) + (ac4.y + ac5.y) + (ac6.y + ac7.y);
  float sz = (ac0.z + ac1.z) + (ac2.z + ac3.z) + (ac4.z + ac5.z) + (ac6.z + ac7.z);
  float sw = (ac0.w + ac1.w) + (ac2.w + ac3.w) + (ac4.w + ac5.w) + (ac6.w + ac7.w);
  uint2 o;
  o.x = pk_bf16(sx, sy);
  o.y = pk_bf16(sz, sw);
  agg[(size_t)node * 32 + hl] = o;
}

// layer-1 aggregation in F_IN=4 space: 4 threads/node, exact-cnt loop
// (x0 is the raw input -- no zero row, so no sentinel padding here).
__global__ void k_agg4b(const float* __restrict__ x, const int* __restrict__ fcnt,
                        const int* __restrict__ colp, float* __restrict__ agg4) {
  int t = blockIdx.x * blockDim.x + threadIdx.x;
  int node = t >> 2, q = t & 3;
  if (node >= NN) return;
  int cnt = fcnt[node];
  if (cnt > DMAX) cnt = DMAX;
  const int* cp = colp + (node << 6);
  float4 acc = make_float4(0.f, 0.f, 0.f, 0.f);
  for (int e = q; e < cnt; e += 4) {
    float4 v = ((const float4*)x)[cp[e]];
    acc.x += v.x; acc.y += v.y; acc.z += v.z; acc.w += v.w;
  }
#pragma unroll
  for (int d = 1; d < 4; d <<= 1) {
    acc.x += __shfl_xor(acc.x, d);
    acc.y += __shfl_xor(acc.y, d);
    acc.z += __shfl_xor(acc.z, d);
    acc.w += __shfl_xor(acc.w, d);
  }
  if (q == 0) ((float4*)agg4)[node] = acc;
}

// ---------------- layer-1 GEMM (K=4+4), fp32 math, bf16 output -------------
__global__ void k_gemm4(const float* __restrict__ agg4, const float* __restrict__ x4,
                        const float* __restrict__ Wr, const float* __restrict__ Wo,
                        const float* __restrict__ br, __hip_bfloat16* __restrict__ out) {
  __shared__ float sWr[512], sWo[512], sbr[128];
  int tid = threadIdx.x;
  sWr[tid] = Wr[tid]; sWr[tid + 256] = Wr[tid + 256];
  sWo[tid] = Wo[tid]; sWo[tid + 256] = Wo[tid + 256];
  if (tid < 128) sbr[tid] = br[tid];
  __syncthreads();
  int node = blockIdx.x * 2 + (tid >> 7);
  int j = tid & 127;
  if (node >= NN) return;
  float4 a = ((const float4*)agg4)[node];
  float4 xv = ((const float4*)x4)[node];
  float acc = sbr[j];
  acc = fmaf(a.x, sWr[0 * 128 + j], acc);
  acc = fmaf(a.y, sWr[1 * 128 + j], acc);
  acc = fmaf(a.z, sWr[2 * 128 + j], acc);
  acc = fmaf(a.w, sWr[3 * 128 + j], acc);
  acc = fmaf(xv.x, sWo[0 * 128 + j], acc);
  acc = fmaf(xv.y, sWo[1 * 128 + j], acc);
  acc = fmaf(xv.z, sWo[2 * 128 + j], acc);
  acc = fmaf(xv.w, sWo[3 * 128 + j], acc);
  out[(size_t)node * H + j] = __float2bfloat16(fmaxf(acc, 0.f));
}

// ---------------- W -> B-fragment-order bf16 conversion (all 3 layers) -----
__global__ void k_wcvt3(const float* __restrict__ Wr1, const float* __restrict__ Wo1,
                        const float* __restrict__ Wr2, const float* __restrict__ Wo2,
                        const float* __restrict__ Wr3, const float* __restrict__ Wo3,
                        __hip_bfloat16* __restrict__ wf) {
  int t = blockIdx.x * 256 + threadIdx.x;  // 3*32768 total
  int L = t >> 15, tt = t & 32767;
  const float* Wr = (L == 0) ? Wr1 : (L == 1) ? Wr2 : Wr3;
  const float* Wo = (L == 0) ? Wo1 : (L == 1) ? Wo2 : Wo3;
  int j = tt & 7, quad = (tt >> 3) & 3, n = (tt >> 5) & 127, kt = tt >> 12;
  int r = kt * 32 + quad * 8 + j;
  float v = (r < 128) ? Wr[r * 128 + n] : Wo[(r - 128) * 128 + n];
  wf[t] = __float2bfloat16(v);
}

// ---------------- MFMA GEMM: relu([agg|x] @ [Wr;Wo] + br) ------------------
__global__ __launch_bounds__(256) void k_gemm_mfma(
    const __hip_bfloat16* __restrict__ A, const __hip_bfloat16* __restrict__ X,
    const __hip_bfloat16* __restrict__ Wf, const float* __restrict__ br,
    __hip_bfloat16* __restrict__ out) {
  const int tid = threadIdx.x;
  const int wv = tid >> 6, lane = tid & 63;
  const int quad = lane >> 4, lr = lane & 15;
  const int mbase = blockIdx.x * 128 + wv * 32;

  floatx4 acc[2][8];
#pragma unroll
  for (int rt = 0; rt < 2; ++rt)
#pragma unroll
    for (int ct = 0; ct < 8; ++ct) acc[rt][ct] = (floatx4){0.f, 0.f, 0.f, 0.f};

  int r0 = mbase + lr;      if (r0 > NN - 1) r0 = NN - 1;
  int r1 = mbase + 16 + lr; if (r1 > NN - 1) r1 = NN - 1;

#pragma unroll
  for (int kt = 0; kt < 8; ++kt) {
    const __hip_bfloat16* base = (kt < 4) ? A : X;
    const size_t koff = (size_t)(kt & 3) * 32 + quad * 8;
    short8 a0 = *(const short8*)(base + (size_t)r0 * H + koff);
    short8 a1 = *(const short8*)(base + (size_t)r1 * H + koff);
    const __hip_bfloat16* wb = Wf + (size_t)kt * 4096 + (size_t)lr * 32 + quad * 8;
#pragma unroll
    for (int ct = 0; ct < 8; ++ct) {
      short8 b = *(const short8*)(wb + ct * 16 * 32);
      acc[0][ct] = __builtin_amdgcn_mfma_f32_16x16x32_bf16(a0, b, acc[0][ct], 0, 0, 0);
      acc[1][ct] = __builtin_amdgcn_mfma_f32_16x16x32_bf16(a1, b, acc[1][ct], 0, 0, 0);
    }
  }

  // C/D layout: col = lane&15, row = quad*4 + reg  [m89-verified]
#pragma unroll
  for (int rt = 0; rt < 2; ++rt) {
    int row0 = mbase + rt * 16 + quad * 4;
#pragma unroll
    for (int ct = 0; ct < 8; ++ct) {
      int n = ct * 16 + lr;
      float bias = br[n];
#pragma unroll
      for (int rg = 0; rg < 4; ++rg) {
        int row = row0 + rg;
        if (row < NN) {
          float v = fmaxf(acc[rt][ct][rg] + bias, 0.f);
          out[(size_t)row * H + n] = __float2bfloat16(v);
        }
      }
    }
  }
}

// ---------------- pooling + head ----------------
#define POOL_TILE 128
__global__ void k_pool2(const __hip_bfloat16* __restrict__ x, const int* __restrict__ batch,
                        float* __restrict__ gsum) {
  int n0 = blockIdx.x * POOL_TILE;
  int j = threadIdx.x;
  int end = n0 + POOL_TILE;
  if (end > NN) end = NN;
  if (n0 >= NN) return;
  int cur_g = batch[n0];
  float acc = 0.f;
  for (int i = n0; i < end; ++i) {
    int g = batch[i];  // wave-uniform load, cache-broadcast
    if (g != cur_g) {
      atomicAdd(&gsum[cur_g * H + j], acc);
      acc = 0.f;
      cur_g = g;
    }
    acc += __bfloat162float(x[(size_t)i * H + j]);
  }
  atomicAdd(&gsum[cur_g * H + j], acc);
}

__global__ void k_head2(const float* __restrict__ gsum, const int* __restrict__ batch,
                        const float* __restrict__ W5, const float* __restrict__ b5,
                        const float* __restrict__ W6, const float* __restrict__ b6,
                        const float* __restrict__ W7, const float* __restrict__ b7,
                        const float* __restrict__ W8, const float* __restrict__ b8,
                        const float* __restrict__ Wl, const float* __restrict__ bl,
                        float* __restrict__ out) {
  __shared__ float s0[128], s1[128];
  __shared__ int sb[2];
  const int g = blockIdx.x, j = threadIdx.x;
  if (j < 2) {  // binary search for bounds of graph g (batch sorted)
    int tgt = g + j, lo = 0, hi = NN;
    while (lo < hi) {
      int mid = (lo + hi) >> 1;
      if (batch[mid] < tgt) lo = mid + 1; else hi = mid;
    }
    sb[j] = lo;
  }
  __syncthreads();
  float cnt = (float)(sb[1] - sb[0]);
  s0[j] = gsum[g * 128 + j] / fmaxf(cnt, 1.f);
  __syncthreads();
  const float* Ws[4] = {W5, W6, W7, W8};
  const float* bs[4] = {b5, b6, b7, b8};
  float* cur = s0;
  float* nxt = s1;
  for (int L = 0; L < 4; ++L) {
    const float* W = Ws[L];
    float a = bs[L][j];
    for (int k = 0; k < 128; ++k) a = fmaf(cur[k], W[k * 128 + j], a);
    nxt[j] = fmaxf(a, 0.f);
    __syncthreads();
    float* t = cur; cur = nxt; nxt = t;
  }
  if (j < 2) {
    float a = bl[j];
    for (int k = 0; k < 128; ++k) a = fmaf(cur[k], Wl[k * 2 + j], a);
    out[g * 2 + j] = 1.f / (1.f + __expf(-a));
  }
}

// ---------------- launch ----------------
static inline char* ws_take(char*& p, size_t bytes) {
  char* r = p;
  p += (bytes + 255) & ~(size_t)255;
  return r;
}

extern "C" void kernel_launch(void* const* d_in, const int* in_sizes, int n_in,
                              void* d_out, int out_size, void* d_ws, size_t ws_size,
                              hipStream_t stream) {
  const float* x0 = (const float*)d_in[0];
  const int* ei = (const int*)d_in[1];
  const int* batch = (const int*)d_in[2];
  const float* Wr[4] = {(const float*)d_in[3], (const float*)d_in[6],
                        (const float*)d_in[9], (const float*)d_in[12]};
  const float* brr[4] = {(const float*)d_in[4], (const float*)d_in[7],
                         (const float*)d_in[10], (const float*)d_in[13]};
  const float* Wo[4] = {(const float*)d_in[5], (const float*)d_in[8],
                        (const float*)d_in[11], (const float*)d_in[14]};
  const float* W5 = (const float*)d_in[15];
  const float* b5 = (const float*)d_in[16];
  const float* W6 = (const float*)d_in[17];
  const float* b6 = (const float*)d_in[18];
  const float* W7 = (const float*)d_in[19];
  const float* b7 = (const float*)d_in[20];
  const float* W8 = (const float*)d_in[21];
  const float* b8 = (const float*)d_in[22];
  const float* Wl = (const float*)d_in[23];
  const float* bl = (const float*)d_in[24];
  float* out = (float*)d_out;

  char* p = (char*)d_ws;
  int* fcnt = (int*)ws_take(p, (size_t)NN * 4);
  int* colp = (int*)ws_take(p, (size_t)NN * DMAX * 4);
  __hip_bfloat16* agg = (__hip_bfloat16*)ws_take(p, (size_t)NN * H * 2);
  __hip_bfloat16* bufA = (__hip_bfloat16*)ws_take(p, (size_t)(NN + 1) * H * 2);
  __hip_bfloat16* bufB = (__hip_bfloat16*)ws_take(p, (size_t)(NN + 1) * H * 2);
  float* agg4 = (float*)ws_take(p, (size_t)NN * 4 * 4);
  float* gsum = (float*)ws_take(p, (size_t)NG * H * 4);
  __hip_bfloat16* wfall = (__hip_bfloat16*)ws_take(p, 3 * 32768 * 2);
  __hip_bfloat16* wf1 = wfall;
  __hip_bfloat16* wf2 = wfall + 32768;
  __hip_bfloat16* wf3 = wfall + 65536;
  (void)ws_size; (void)in_sizes; (void)n_in; (void)out_size;

  hipMemsetAsync(fcnt, 0, (size_t)NN * 4, stream);
  hipMemsetAsync(gsum, 0, (size_t)NG * H * 4, stream);
  // zero the sentinel row NN of bufA/bufB (gather target for padded slots)
  hipMemsetAsync(bufA + (size_t)NN * H, 0, H * 2, stream);
  hipMemsetAsync(bufB + (size_t)NN * H, 0, H * 2, stream);
  k_wcvt3<<<384, 256, 0, stream>>>(Wr[1], Wo[1], Wr[2], Wo[2], Wr[3], Wo[3], wfall);
  k_fillpad<<<1024, 256, 0, stream>>>(ei, fcnt, colp);
  k_padtail<<<(NN + 255) / 256, 256, 0, stream>>>(fcnt, colp);

  // layer 1 (F_IN=4): aggregate in input space, then small GEMM -> bf16
  k_agg4b<<<(NN * 4 + 255) / 256, 256, 0, stream>>>(x0, fcnt, colp, agg4);
  k_gemm4<<<NN / 2, 256, 0, stream>>>(agg4, x0, Wr[0], Wo[0], brr[0], bufA);

  // layers 2-4: bf16 gather-agg + MFMA GEMM
  k_aggbf2<<<12500, 256, 0, stream>>>((const uint2*)bufA, fcnt, colp, (uint2*)agg);
  k_gemm_mfma<<<782, 256, 0, stream>>>(agg, bufA, wf1, brr[1], bufB);
  k_aggbf2<<<12500, 256, 0, stream>>>((const uint2*)bufB, fcnt, colp, (uint2*)agg);
  k_gemm_mfma<<<782, 256, 0, stream>>>(agg, bufB, wf2, brr[2], bufA);
  k_aggbf2<<<12500, 256, 0, stream>>>((const uint2*)bufA, fcnt, colp, (uint2*)agg);
  k_gemm_mfma<<<782, 256, 0, stream>>>(agg, bufA, wf3, brr[3], bufB);

  // mean pool + MLP head + sigmoid
  k_pool2<<<(NN + POOL_TILE - 1) / POOL_TILE, 128, 0, stream>>>(bufB, batch, gsum);
  k_head2<<<NG, 128, 0, stream>>>(gsum, batch, W5, b5, W6, b6, W7, b7, W8, b8, Wl, bl, out);
}

// Round 8
// 603.169 us; speedup vs baseline: 2.1632x; 1.0017x over previous
//
#include <hip/hip_runtime.h>
#include <hip/hip_bf16.h>
#include <math.h>

#define NN 100000
#define NE 1600000
#define NG 128
#define H 128
#define RANGE 12500  // NN/8 : dst-range per XCD group
#define DMAX 64      // padded CSR slots/node; P(deg>64 | Poisson16) ~ 1e-17

typedef __attribute__((ext_vector_type(8))) short short8;
typedef __attribute__((ext_vector_type(4))) float floatx4;

// ---------------- padded-bucket CSR build (no hist, no scan) ---------------
// blockIdx&7 pins each dst-range to one XCD; atomics + col writes confined to
// 3.2 MB -> that XCD's L2. R6 lesson: store-inside-if forced a waitcnt per
// atomic (VALUBusy 5%). Now: 4 atomics issued back-to-back (results unused in
// their own blocks), THEN 4 predicated stores -> one wait covers 4 atomics.
__global__ void k_fillpad(const int* __restrict__ ei, int* __restrict__ fcnt,
                          int* __restrict__ colp) {
  int g = blockIdx.x & 7;
  int j = blockIdx.x >> 3;  // 0..127
  int lo = g * RANGE, hi = lo + RANGE;
  const int* dst = ei + NE;
  int tid = threadIdx.x;
  for (int base = j * 1024; base < NE; base += 128 * 1024) {
    int e0 = base + tid, e1 = e0 + 256, e2 = e0 + 512, e3 = e0 + 768;
    int d0 = (e0 < NE) ? dst[e0] : -1;
    int d1 = (e1 < NE) ? dst[e1] : -1;
    int d2 = (e2 < NE) ? dst[e2] : -1;
    int d3 = (e3 < NE) ? dst[e3] : -1;
    int s0 = (e0 < NE) ? ei[e0] : 0;
    int s1 = (e1 < NE) ? ei[e1] : 0;
    int s2 = (e2 < NE) ? ei[e2] : 0;
    int s3 = (e3 < NE) ? ei[e3] : 0;
    int p0 = -1, p1 = -1, p2 = -1, p3 = -1;
    // phase 1: atomics only (no dependent use inside the divergent regions)
    if (d0 >= lo && d0 < hi) p0 = atomicAdd(&fcnt[d0], 1);
    if (d1 >= lo && d1 < hi) p1 = atomicAdd(&fcnt[d1], 1);
    if (d2 >= lo && d2 < hi) p2 = atomicAdd(&fcnt[d2], 1);
    if (d3 >= lo && d3 < hi) p3 = atomicAdd(&fcnt[d3], 1);
    // phase 2: stores (single waitcnt drains all 4 atomic returns)
    if (p0 >= 0 && p0 < DMAX) colp[(d0 << 6) + p0] = s0;
    if (p1 >= 0 && p1 < DMAX) colp[(d1 << 6) + p1] = s1;
    if (p2 >= 0 && p2 < DMAX) colp[(d2 << 6) + p2] = s2;
    if (p3 >= 0 && p3 < DMAX) colp[(d3 << 6) + p3] = s3;
  }
}

// pad each node's bucket to a multiple of 4 with sentinel NN (a zeroed row in
// bufA/bufB) -> aggbf3 runs a tail-free 4-deep gather loop.
__global__ void k_padtail(const int* __restrict__ fcnt, int* __restrict__ colp) {
  int node = blockIdx.x * 256 + threadIdx.x;
  if (node >= NN) return;
  int cnt = fcnt[node];
  if (cnt > DMAX) cnt = DMAX;
  int up = (cnt + 3) & ~3;
  for (int i = cnt; i < up; ++i) colp[(node << 6) + i] = NN;
}

// ---------------- bf16 helpers ----------------
__device__ inline unsigned pk_bf16(float a, float b) {  // RNE pack (lo=a, hi=b)
  unsigned ua = __float_as_uint(a), ub = __float_as_uint(b);
  ua = (ua + 0x7fffu + ((ua >> 16) & 1u)) >> 16;
  ub = (ub + 0x7fffu + ((ub >> 16) & 1u)) & 0xffff0000u;
  return ua | ub;
}

__device__ inline void acc8(float* a, uint4 u) {  // 8 packed bf16 += into fp32
  a[0] += __uint_as_float(u.x << 16);
  a[1] += __uint_as_float(u.x & 0xffff0000u);
  a[2] += __uint_as_float(u.y << 16);
  a[3] += __uint_as_float(u.y & 0xffff0000u);
  a[4] += __uint_as_float(u.z << 16);
  a[5] += __uint_as_float(u.z & 0xffff0000u);
  a[6] += __uint_as_float(u.w << 16);
  a[7] += __uint_as_float(u.w & 0xffff0000u);
}

// ---------------- aggregation (bf16 x, fp32 accumulate, bf16 agg) ----------
// 16 B/lane (uint4): 16 lanes/row (row = 256 B = 16 uint4 -> stride 16; R7's
// failure was stride 8 here), 4 nodes/wave, depth-4 = same bytes and lines
// per edge as the uint2 version, HALF the gather instructions. Buckets padded
// to x4 with zero-row sentinel NN -> tail-free.
__global__ void k_aggbf3(const uint4* __restrict__ xx, const int* __restrict__ fcnt,
                         const int* __restrict__ colp, uint4* __restrict__ agg) {
  int w = (blockIdx.x * blockDim.x + threadIdx.x) >> 6;
  int lane = threadIdx.x & 63;
  int qr = lane >> 4, ql = lane & 15;  // qr: node-of-wave, ql: 16B chunk of row
  int node = 4 * w + qr;
  if (node >= NN) return;
  int cnt = fcnt[node];
  if (cnt > DMAX) cnt = DMAX;
  cnt = (cnt + 3) & ~3;
  const int* cp = colp + (node << 6);
  float a0[8] = {0}, a1[8] = {0}, a2[8] = {0}, a3[8] = {0};
  for (int i = 0; i < cnt; i += 4) {
    int4 ss = *(const int4*)(cp + i);  // 16B-aligned bucket chunk
    uint4 u0 = xx[(size_t)ss.x * 16 + ql];
    uint4 u1 = xx[(size_t)ss.y * 16 + ql];
    uint4 u2 = xx[(size_t)ss.z * 16 + ql];
    uint4 u3 = xx[(size_t)ss.w * 16 + ql];
    acc8(a0, u0);
    acc8(a1, u1);
    acc8(a2, u2);
    acc8(a3, u3);
  }
  float s[8];
#pragma unroll
  for (int t = 0; t < 8; ++t) s[t] = (a0[t] + a1[t]) + (a2[t] + a3[t]);
  uint4 o;
  o.x = pk_bf16(s[0], s[1]);
  o.y = pk_bf16(s[2], s[3]);
  o.z = pk_bf16(s[4], s[5]);
  o.w = pk_bf16(s[6], s[7]);
  agg[(size_t)node * 16 + ql] = o;
}

// layer-1 aggregation in F_IN=4 space: 4 threads/node, exact-cnt loop
// (x0 is the raw input -- no zero row; sentinel slots skipped via exact fcnt).
__global__ void k_agg4b(const float* __restrict__ x, const int* __restrict__ fcnt,
                        const int* __restrict__ colp, float* __restrict__ agg4) {
  int t = blockIdx.x * blockDim.x + threadIdx.x;
  int node = t >> 2, q = t & 3;
  if (node >= NN) return;
  int cnt = fcnt[node];
  if (cnt > DMAX) cnt = DMAX;
  const int* cp = colp + (node << 6);
  float4 acc = make_float4(0.f, 0.f, 0.f, 0.f);
  for (int e = q; e < cnt; e += 4) {
    float4 v = ((const float4*)x)[cp[e]];
    acc.x += v.x; acc.y += v.y; acc.z += v.z; acc.w += v.w;
  }
#pragma unroll
  for (int d = 1; d < 4; d <<= 1) {
    acc.x += __shfl_xor(acc.x, d);
    acc.y += __shfl_xor(acc.y, d);
    acc.z += __shfl_xor(acc.z, d);
    acc.w += __shfl_xor(acc.w, d);
  }
  if (q == 0) ((float4*)agg4)[node] = acc;
}

// ---------------- layer-1 GEMM (K=4+4), fp32 math, bf16 output -------------
__global__ void k_gemm4(const float* __restrict__ agg4, const float* __restrict__ x4,
                        const float* __restrict__ Wr, const float* __restrict__ Wo,
                        const float* __restrict__ br, __hip_bfloat16* __restrict__ out) {
  __shared__ float sWr[512], sWo[512], sbr[128];
  int tid = threadIdx.x;
  sWr[tid] = Wr[tid]; sWr[tid + 256] = Wr[tid + 256];
  sWo[tid] = Wo[tid]; sWo[tid + 256] = Wo[tid + 256];
  if (tid < 128) sbr[tid] = br[tid];
  __syncthreads();
  int node = blockIdx.x * 2 + (tid >> 7);
  int j = tid & 127;
  if (node >= NN) return;
  float4 a = ((const float4*)agg4)[node];
  float4 xv = ((const float4*)x4)[node];
  float acc = sbr[j];
  acc = fmaf(a.x, sWr[0 * 128 + j], acc);
  acc = fmaf(a.y, sWr[1 * 128 + j], acc);
  acc = fmaf(a.z, sWr[2 * 128 + j], acc);
  acc = fmaf(a.w, sWr[3 * 128 + j], acc);
  acc = fmaf(xv.x, sWo[0 * 128 + j], acc);
  acc = fmaf(xv.y, sWo[1 * 128 + j], acc);
  acc = fmaf(xv.z, sWo[2 * 128 + j], acc);
  acc = fmaf(xv.w, sWo[3 * 128 + j], acc);
  out[(size_t)node * H + j] = __float2bfloat16(fmaxf(acc, 0.f));
}

// ---------------- W -> B-fragment-order bf16 conversion (all 3 layers) -----
__global__ void k_wcvt3(const float* __restrict__ Wr1, const float* __restrict__ Wo1,
                        const float* __restrict__ Wr2, const float* __restrict__ Wo2,
                        const float* __restrict__ Wr3, const float* __restrict__ Wo3,
                        __hip_bfloat16* __restrict__ wf) {
  int t = blockIdx.x * 256 + threadIdx.x;  // 3*32768 total
  int L = t >> 15, tt = t & 32767;
  const float* Wr = (L == 0) ? Wr1 : (L == 1) ? Wr2 : Wr3;
  const float* Wo = (L == 0) ? Wo1 : (L == 1) ? Wo2 : Wo3;
  int j = tt & 7, quad = (tt >> 3) & 3, n = (tt >> 5) & 127, kt = tt >> 12;
  int r = kt * 32 + quad * 8 + j;
  float v = (r < 128) ? Wr[r * 128 + n] : Wo[(r - 128) * 128 + n];
  wf[t] = __float2bfloat16(v);
}

// ---------------- MFMA GEMM: relu([agg|x] @ [Wr;Wo] + br) ------------------
__global__ __launch_bounds__(256) void k_gemm_mfma(
    const __hip_bfloat16* __restrict__ A, const __hip_bfloat16* __restrict__ X,
    const __hip_bfloat16* __restrict__ Wf, const float* __restrict__ br,
    __hip_bfloat16* __restrict__ out) {
  const int tid = threadIdx.x;
  const int wv = tid >> 6, lane = tid & 63;
  const int quad = lane >> 4, lr = lane & 15;
  const int mbase = blockIdx.x * 128 + wv * 32;

  floatx4 acc[2][8];
#pragma unroll
  for (int rt = 0; rt < 2; ++rt)
#pragma unroll
    for (int ct = 0; ct < 8; ++ct) acc[rt][ct] = (floatx4){0.f, 0.f, 0.f, 0.f};

  int r0 = mbase + lr;      if (r0 > NN - 1) r0 = NN - 1;
  int r1 = mbase + 16 + lr; if (r1 > NN - 1) r1 = NN - 1;

#pragma unroll
  for (int kt = 0; kt < 8; ++kt) {
    const __hip_bfloat16* base = (kt < 4) ? A : X;
    const size_t koff = (size_t)(kt & 3) * 32 + quad * 8;
    short8 a0 = *(const short8*)(base + (size_t)r0 * H + koff);
    short8 a1 = *(const short8*)(base + (size_t)r1 * H + koff);
    const __hip_bfloat16* wb = Wf + (size_t)kt * 4096 + (size_t)lr * 32 + quad * 8;
#pragma unroll
    for (int ct = 0; ct < 8; ++ct) {
      short8 b = *(const short8*)(wb + ct * 16 * 32);
      acc[0][ct] = __builtin_amdgcn_mfma_f32_16x16x32_bf16(a0, b, acc[0][ct], 0, 0, 0);
      acc[1][ct] = __builtin_amdgcn_mfma_f32_16x16x32_bf16(a1, b, acc[1][ct], 0, 0, 0);
    }
  }

  // C/D layout: col = lane&15, row = quad*4 + reg  [m89-verified]
#pragma unroll
  for (int rt = 0; rt < 2; ++rt) {
    int row0 = mbase + rt * 16 + quad * 4;
#pragma unroll
    for (int ct = 0; ct < 8; ++ct) {
      int n = ct * 16 + lr;
      float bias = br[n];
#pragma unroll
      for (int rg = 0; rg < 4; ++rg) {
        int row = row0 + rg;
        if (row < NN) {
          float v = fmaxf(acc[rt][ct][rg] + bias, 0.f);
          out[(size_t)row * H + n] = __float2bfloat16(v);
        }
      }
    }
  }
}

// ---------------- pooling + head ----------------
#define POOL_TILE 128
__global__ void k_pool2(const __hip_bfloat16* __restrict__ x, const int* __restrict__ batch,
                        float* __restrict__ gsum) {
  int n0 = blockIdx.x * POOL_TILE;
  int j = threadIdx.x;
  int end = n0 + POOL_TILE;
  if (end > NN) end = NN;
  if (n0 >= NN) return;
  int cur_g = batch[n0];
  float acc = 0.f;
  for (int i = n0; i < end; ++i) {
    int g = batch[i];  // wave-uniform load, cache-broadcast
    if (g != cur_g) {
      atomicAdd(&gsum[cur_g * H + j], acc);
      acc = 0.f;
      cur_g = g;
    }
    acc += __bfloat162float(x[(size_t)i * H + j]);
  }
  atomicAdd(&gsum[cur_g * H + j], acc);
}

__global__ void k_head2(const float* __restrict__ gsum, const int* __restrict__ batch,
                        const float* __restrict__ W5, const float* __restrict__ b5,
                        const float* __restrict__ W6, const float* __restrict__ b6,
                        const float* __restrict__ W7, const float* __restrict__ b7,
                        const float* __restrict__ W8, const float* __restrict__ b8,
                        const float* __restrict__ Wl, const float* __restrict__ bl,
                        float* __restrict__ out) {
  __shared__ float s0[128], s1[128];
  __shared__ int sb[2];
  const int g = blockIdx.x, j = threadIdx.x;
  if (j < 2) {  // binary search for bounds of graph g (batch sorted)
    int tgt = g + j, lo = 0, hi = NN;
    while (lo < hi) {
      int mid = (lo + hi) >> 1;
      if (batch[mid] < tgt) lo = mid + 1; else hi = mid;
    }
    sb[j] = lo;
  }
  __syncthreads();
  float cnt = (float)(sb[1] - sb[0]);
  s0[j] = gsum[g * 128 + j] / fmaxf(cnt, 1.f);
  __syncthreads();
  const float* Ws[4] = {W5, W6, W7, W8};
  const float* bs[4] = {b5, b6, b7, b8};
  float* cur = s0;
  float* nxt = s1;
  for (int L = 0; L < 4; ++L) {
    const float* W = Ws[L];
    float a = bs[L][j];
    for (int k = 0; k < 128; ++k) a = fmaf(cur[k], W[k * 128 + j], a);
    nxt[j] = fmaxf(a, 0.f);
    __syncthreads();
    float* t = cur; cur = nxt; nxt = t;
  }
  if (j < 2) {
    float a = bl[j];
    for (int k = 0; k < 128; ++k) a = fmaf(cur[k], Wl[k * 2 + j], a);
    out[g * 2 + j] = 1.f / (1.f + __expf(-a));
  }
}

// ---------------- launch ----------------
static inline char* ws_take(char*& p, size_t bytes) {
  char* r = p;
  p += (bytes + 255) & ~(size_t)255;
  return r;
}

extern "C" void kernel_launch(void* const* d_in, const int* in_sizes, int n_in,
                              void* d_out, int out_size, void* d_ws, size_t ws_size,
                              hipStream_t stream) {
  const float* x0 = (const float*)d_in[0];
  const int* ei = (const int*)d_in[1];
  const int* batch = (const int*)d_in[2];
  const float* Wr[4] = {(const float*)d_in[3], (const float*)d_in[6],
                        (const float*)d_in[9], (const float*)d_in[12]};
  const float* brr[4] = {(const float*)d_in[4], (const float*)d_in[7],
                         (const float*)d_in[10], (const float*)d_in[13]};
  const float* Wo[4] = {(const float*)d_in[5], (const float*)d_in[8],
                        (const float*)d_in[11], (const float*)d_in[14]};
  const float* W5 = (const float*)d_in[15];
  const float* b5 = (const float*)d_in[16];
  const float* W6 = (const float*)d_in[17];
  const float* b6 = (const float*)d_in[18];
  const float* W7 = (const float*)d_in[19];
  const float* b7 = (const float*)d_in[20];
  const float* W8 = (const float*)d_in[21];
  const float* b8 = (const float*)d_in[22];
  const float* Wl = (const float*)d_in[23];
  const float* bl = (const float*)d_in[24];
  float* out = (float*)d_out;

  char* p = (char*)d_ws;
  int* fcnt = (int*)ws_take(p, (size_t)NN * 4);
  int* colp = (int*)ws_take(p, (size_t)NN * DMAX * 4);
  __hip_bfloat16* agg = (__hip_bfloat16*)ws_take(p, (size_t)NN * H * 2);
  __hip_bfloat16* bufA = (__hip_bfloat16*)ws_take(p, (size_t)(NN + 1) * H * 2);
  __hip_bfloat16* bufB = (__hip_bfloat16*)ws_take(p, (size_t)(NN + 1) * H * 2);
  float* agg4 = (float*)ws_take(p, (size_t)NN * 4 * 4);
  float* gsum = (float*)ws_take(p, (size_t)NG * H * 4);
  __hip_bfloat16* wfall = (__hip_bfloat16*)ws_take(p, 3 * 32768 * 2);
  __hip_bfloat16* wf1 = wfall;
  __hip_bfloat16* wf2 = wfall + 32768;
  __hip_bfloat16* wf3 = wfall + 65536;
  (void)ws_size; (void)in_sizes; (void)n_in; (void)out_size;

  hipMemsetAsync(fcnt, 0, (size_t)NN * 4, stream);
  hipMemsetAsync(gsum, 0, (size_t)NG * H * 4, stream);
  // zero the sentinel row NN of bufA/bufB (gather target for padded slots)
  hipMemsetAsync(bufA + (size_t)NN * H, 0, H * 2, stream);
  hipMemsetAsync(bufB + (size_t)NN * H, 0, H * 2, stream);
  k_wcvt3<<<384, 256, 0, stream>>>(Wr[1], Wo[1], Wr[2], Wo[2], Wr[3], Wo[3], wfall);
  k_fillpad<<<1024, 256, 0, stream>>>(ei, fcnt, colp);
  k_padtail<<<(NN + 255) / 256, 256, 0, stream>>>(fcnt, colp);

  // layer 1 (F_IN=4): aggregate in input space, then small GEMM -> bf16
  k_agg4b<<<(NN * 4 + 255) / 256, 256, 0, stream>>>(x0, fcnt, colp, agg4);
  k_gemm4<<<NN / 2, 256, 0, stream>>>(agg4, x0, Wr[0], Wo[0], brr[0], bufA);

  // layers 2-4: bf16 gather-agg + MFMA GEMM
  k_aggbf3<<<6250, 256, 0, stream>>>((const uint4*)bufA, fcnt, colp, (uint4*)agg);
  k_gemm_mfma<<<782, 256, 0, stream>>>(agg, bufA, wf1, brr[1], bufB);
  k_aggbf3<<<6250, 256, 0, stream>>>((const uint4*)bufB, fcnt, colp, (uint4*)agg);
  k_gemm_mfma<<<782, 256, 0, stream>>>(agg, bufB, wf2, brr[2], bufA);
  k_aggbf3<<<6250, 256, 0, stream>>>((const uint4*)bufA, fcnt, colp, (uint4*)agg);
  k_gemm_mfma<<<782, 256, 0, stream>>>(agg, bufA, wf3, brr[3], bufB);

  // mean pool + MLP head + sigmoid
  k_pool2<<<(NN + POOL_TILE - 1) / POOL_TILE, 128, 0, stream>>>(bufB, batch, gsum);
  k_head2<<<NG, 128, 0, stream>>>(gsum, batch, W5, b5, W6, b6, W7, b7, W8, b8, Wl, bl, out);
}